// Round 3
// baseline (573.461 us; speedup 1.0000x reference)
//
#include <hip/hip_runtime.h>

#define N_NODES 100000
#define N_EDGESC 800000
#define NGRAPH 128
#define DIN 84
#define DHID 840
#define DF1 1024
#define DOUTC 384

typedef __attribute__((ext_vector_type(4))) float f32x4;
typedef __attribute__((ext_vector_type(8))) short bf16x8;

__device__ __forceinline__ unsigned short f2bf(float f) {
  union { float f; unsigned int u; } v; v.f = f;
  unsigned int r = v.u + 0x7FFFu + ((v.u >> 16) & 1u);
  return (unsigned short)(r >> 16);
}
__device__ __forceinline__ float bf2f(unsigned short h) {
  union { unsigned int u; float f; } v; v.u = ((unsigned int)h) << 16;
  return v.f;
}

// ---------------- CSR build ----------------
__global__ __launch_bounds__(256) void k_deg(const int* __restrict__ dst, int* __restrict__ deg) {
  int e = blockIdx.x * 256 + threadIdx.x;
  if (e >= N_EDGESC) return;
  atomicAdd(&deg[dst[e]], 1);
}

#define SCHUNK 1024
#define SBLOCKS 98   // ceil(100000/1024)

__global__ __launch_bounds__(256) void k_scan1(const int* __restrict__ deg, int* __restrict__ bsum) {
  __shared__ int sd[256];
  int b = blockIdx.x, t = threadIdx.x;
  int base = b * SCHUNK + t * 4;
  int s = 0;
  for (int j = 0; j < 4; j++) { int i = base + j; if (i < N_NODES) s += deg[i]; }
  sd[t] = s; __syncthreads();
  for (int off = 128; off > 0; off >>= 1) {
    if (t < off) sd[t] += sd[t + off];
    __syncthreads();
  }
  if (t == 0) bsum[b] = sd[0];
}

__global__ __launch_bounds__(128) void k_scan2(const int* __restrict__ bsum, int* __restrict__ boff) {
  __shared__ int sd[128];
  int t = threadIdx.x;
  int v = (t < SBLOCKS) ? bsum[t] : 0;
  sd[t] = v; __syncthreads();
  for (int off = 1; off < 128; off <<= 1) {
    int add = (t >= off) ? sd[t - off] : 0;
    __syncthreads();
    sd[t] += add;
    __syncthreads();
  }
  if (t < SBLOCKS) boff[t] = sd[t] - v;
}

__global__ __launch_bounds__(256) void k_scan3(const int* __restrict__ deg, const int* __restrict__ boff,
                                               int* __restrict__ rowptr, int* __restrict__ cursor) {
  __shared__ int sd[256];
  int b = blockIdx.x, t = threadIdx.x;
  int base = b * SCHUNK + t * 4;
  int v[4]; int s = 0;
  for (int j = 0; j < 4; j++) { int i = base + j; v[j] = (i < N_NODES) ? deg[i] : 0; s += v[j]; }
  sd[t] = s; __syncthreads();
  for (int off = 1; off < 256; off <<= 1) {
    int add = (t >= off) ? sd[t - off] : 0;
    __syncthreads();
    sd[t] += add;
    __syncthreads();
  }
  int run = sd[t] - s + boff[b];
  for (int j = 0; j < 4; j++) {
    int i = base + j;
    if (i < N_NODES) { rowptr[i] = run; cursor[i] = run; }
    run += v[j];
  }
  if (b == 0 && t == 0) rowptr[N_NODES] = N_EDGESC;
}

__global__ __launch_bounds__(256) void k_fill(const int* __restrict__ src, const int* __restrict__ dst,
                                              int* __restrict__ cursor, int* __restrict__ csr) {
  int e = blockIdx.x * 256 + threadIdx.x;
  if (e >= N_EDGESC) return;
  int d = dst[e];
  int pos = atomicAdd(&cursor[d], 1);
  csr[pos] = src[e];
}

// ---------------- per-graph node counts ----------------
__global__ __launch_bounds__(256) void k_counts(const int* __restrict__ batch, int* __restrict__ cnt) {
  __shared__ int h[NGRAPH];
  int t = threadIdx.x;
  if (t < NGRAPH) h[t] = 0;
  __syncthreads();
  int base = blockIdx.x * 2048;
  for (int j = 0; j < 8; j++) {
    int i = base + j * 256 + t;
    if (i < N_NODES) atomicAdd(&h[batch[i]], 1);
  }
  __syncthreads();
  if (t < NGRAPH && h[t] > 0) atomicAdd(&cnt[t], h[t]);
}

// ---------------- aggregation: out[i] = x[i] + sum_{e in in(i)} x[src_e] ----------------
// BF16OUT=false: f32 out, row stride 84.  BF16OUT=true: bf16 out, row stride 96, zero pad cols 84..95.
template <bool BF16OUT>
__global__ __launch_bounds__(256) void k_agg(const float* __restrict__ xin, const int* __restrict__ rowptr,
                                             const int* __restrict__ csr, void* __restrict__ outv) {
  int node = blockIdx.x * 8 + (threadIdx.x >> 5);
  int lane = threadIdx.x & 31;
  if (node >= N_NODES) return;
  int r0 = rowptr[node], r1 = rowptr[node + 1];
  const f32x4* x4 = (const f32x4*)xin;
  bool act = lane < 21;
  f32x4 a = {0.f, 0.f, 0.f, 0.f};
  if (act) a = x4[node * 21 + lane];
  int e = r0;
  for (; e + 4 <= r1; e += 4) {
    int s0 = csr[e], s1 = csr[e + 1], s2 = csr[e + 2], s3 = csr[e + 3];
    if (act) {
      f32x4 v0 = x4[s0 * 21 + lane];
      f32x4 v1 = x4[s1 * 21 + lane];
      f32x4 v2 = x4[s2 * 21 + lane];
      f32x4 v3 = x4[s3 * 21 + lane];
      a += (v0 + v1) + (v2 + v3);
    }
  }
  for (; e < r1; e++) {
    int s = csr[e];
    if (act) a += x4[s * 21 + lane];
  }
  if (BF16OUT) {
    unsigned short* ob = (unsigned short*)outv;
    if (lane < 24) {
      uint2 p;
      if (act) {
        p.x = (unsigned int)f2bf(a.x) | ((unsigned int)f2bf(a.y) << 16);
        p.y = (unsigned int)f2bf(a.z) | ((unsigned int)f2bf(a.w) << 16);
      } else {
        p.x = 0u; p.y = 0u;   // zero K-pad cols 84..95
      }
      *(uint2*)&ob[node * 96 + lane * 4] = p;
    }
  } else {
    if (act) ((f32x4*)outv)[node * 21 + lane] = a;
  }
}

// ---------------- W1^T split hi/lo bf16, padded [96][96] ----------------
__global__ __launch_bounds__(256) void k_w1t(const float* __restrict__ W1, unsigned short* __restrict__ w1h,
                                             unsigned short* __restrict__ w1l) {
  int idx = blockIdx.x * 256 + threadIdx.x;
  if (idx >= 96 * 96) return;
  int n = idx / 96, k = idx % 96;
  float v = (n < DIN && k < DIN) ? W1[k * DIN + n] : 0.f;
  unsigned short h = f2bf(v);
  w1h[idx] = h;
  w1l[idx] = f2bf(v - bf2f(h));
}

// ---------------- conv1 via MFMA, split-bf16 (hi*hi + lo*hi + hi*lo ~ f32 accuracy) --------
__global__ __launch_bounds__(256) void k_conv1m(const float* __restrict__ agg,
                                                const unsigned short* __restrict__ w1h,
                                                const unsigned short* __restrict__ w1l,
                                                const float* __restrict__ b1, float* __restrict__ h1) {
  constexpr int LDA = 104;
  __shared__ __align__(16) unsigned short Ah[64 * LDA];
  __shared__ __align__(16) unsigned short Al[64 * LDA];
  int t = threadIdx.x;
  int m0 = blockIdx.x * 64;

  for (int idx = t; idx < 64 * 21; idx += 256) {
    int r = idx / 21, c = idx - r * 21;
    int row = m0 + r;
    f32x4 v = {0.f, 0.f, 0.f, 0.f};
    if (row < N_NODES) v = *(const f32x4*)&agg[row * DIN + c * 4];
    unsigned short h0 = f2bf(v.x), h1_ = f2bf(v.y), h2_ = f2bf(v.z), h3_ = f2bf(v.w);
    unsigned short l0 = f2bf(v.x - bf2f(h0)), l1 = f2bf(v.y - bf2f(h1_));
    unsigned short l2 = f2bf(v.z - bf2f(h2_)), l3 = f2bf(v.w - bf2f(h3_));
    unsigned int* ph = (unsigned int*)&Ah[r * LDA + c * 4];
    ph[0] = (unsigned int)h0 | ((unsigned int)h1_ << 16);
    ph[1] = (unsigned int)h2_ | ((unsigned int)h3_ << 16);
    unsigned int* pl = (unsigned int*)&Al[r * LDA + c * 4];
    pl[0] = (unsigned int)l0 | ((unsigned int)l1 << 16);
    pl[1] = (unsigned int)l2 | ((unsigned int)l3 << 16);
  }
  for (int idx = t; idx < 64 * 6; idx += 256) {
    int r = idx / 6, c = idx - r * 6;
    ((unsigned int*)&Ah[r * LDA + 84])[c] = 0;
    ((unsigned int*)&Al[r * LDA + 84])[c] = 0;
  }
  __syncthreads();

  int w = t >> 6, l = t & 63;
  int lr = l & 15, lk = (l >> 4) * 8;
  bf16x8 ah[3], al[3];
  #pragma unroll
  for (int kk = 0; kk < 3; kk++) {
    ah[kk] = *(bf16x8*)&Ah[(w * 16 + lr) * LDA + lk + kk * 32];
    al[kk] = *(bf16x8*)&Al[(w * 16 + lr) * LDA + lk + kk * 32];
  }

  #pragma unroll
  for (int nt = 0; nt < 6; nt++) {
    f32x4 acc = {0.f, 0.f, 0.f, 0.f};
    #pragma unroll
    for (int kk = 0; kk < 3; kk++) {
      bf16x8 bh = *(const bf16x8*)&w1h[(nt * 16 + lr) * 96 + lk + kk * 32];
      bf16x8 bl = *(const bf16x8*)&w1l[(nt * 16 + lr) * 96 + lk + kk * 32];
      acc = __builtin_amdgcn_mfma_f32_16x16x32_bf16(ah[kk], bh, acc, 0, 0, 0);
      acc = __builtin_amdgcn_mfma_f32_16x16x32_bf16(al[kk], bh, acc, 0, 0, 0);
      acc = __builtin_amdgcn_mfma_f32_16x16x32_bf16(ah[kk], bl, acc, 0, 0, 0);
    }
    int col = nt * 16 + lr;
    if (col < DIN) {
      float bias = b1[col];
      int rbase = m0 + w * 16 + (l >> 4) * 4;
      #pragma unroll
      for (int j = 0; j < 4; j++) {
        if (rbase + j < N_NODES)
          h1[(rbase + j) * DIN + col] = fmaxf(acc[j] + bias, 0.f);
      }
    }
  }
}

// ---------------- W2^T in bf16, padded [896][96] ----------------
__global__ __launch_bounds__(256) void k_w2t(const float* __restrict__ W2, unsigned short* __restrict__ w2t) {
  int idx = blockIdx.x * 256 + threadIdx.x;
  if (idx >= 896 * 96) return;
  int n = idx / 96, k = idx % 96;
  float v = (n < DHID && k < DIN) ? W2[k * DHID + n] : 0.f;
  w2t[idx] = f2bf(v);
}

// ---------------- conv2 (bf16 MFMA) + fused max/mean pooling; barrier-free, LDS-free ------
// Block = 64 rows x 4 waves. Each wave holds ALL 64 rows' A fragments in regs and owns
// column-chunks nc = w, w+4, w+8, w+12. B fragments read straight from L2-resident w2t.
__global__ __launch_bounds__(256) void k_conv2pool2(const unsigned short* __restrict__ aggb,
                                                    const unsigned short* __restrict__ w2t,
                                                    const float* __restrict__ b2,
                                                    const int* __restrict__ batch,
                                                    int* __restrict__ maxb, float* __restrict__ sump) {
  int t = threadIdx.x;
  int w = t >> 6, l = t & 63;
  int m0 = blockIdx.x * 64;
  int lr = l & 15, hi = l >> 4;
  int lk = hi * 8;

  // A fragments: 4 row-groups x 3 k-chunks, straight from global bf16 (stride 96)
  bf16x8 afr[4][3];
  #pragma unroll
  for (int rg = 0; rg < 4; rg++) {
    int row = m0 + rg * 16 + lr;
    #pragma unroll
    for (int kk = 0; kk < 3; kk++) {
      bf16x8 v = {0, 0, 0, 0, 0, 0, 0, 0};
      if (row < N_NODES) v = *(const bf16x8*)&aggb[row * 96 + lk + kk * 32];
      afr[rg][kk] = v;
    }
  }

  int g0 = batch[m0];
  bool uni = (m0 + 63 < N_NODES) && (batch[m0 + 63] == g0);

  for (int nc = w; nc < 14; nc += 4) {
    #pragma unroll
    for (int nt = 0; nt < 4; nt++) {
      int c = nc * 64 + nt * 16 + lr;
      const unsigned short* bp = &w2t[(nc * 64 + nt * 16 + lr) * 96 + lk];
      bf16x8 b0 = *(const bf16x8*)(bp);
      bf16x8 b1v = *(const bf16x8*)(bp + 32);
      bf16x8 b2v = *(const bf16x8*)(bp + 64);
      f32x4 acc[4];
      #pragma unroll
      for (int rg = 0; rg < 4; rg++) {
        f32x4 a_ = {0.f, 0.f, 0.f, 0.f};
        a_ = __builtin_amdgcn_mfma_f32_16x16x32_bf16(afr[rg][0], b0, a_, 0, 0, 0);
        a_ = __builtin_amdgcn_mfma_f32_16x16x32_bf16(afr[rg][1], b1v, a_, 0, 0, 0);
        a_ = __builtin_amdgcn_mfma_f32_16x16x32_bf16(afr[rg][2], b2v, a_, 0, 0, 0);
        acc[rg] = a_;
      }
      float bias = (c < DHID) ? b2[c] : 0.f;
      if (uni) {
        float mx = 0.f, sm = 0.f;   // relu'd values are >= 0
        #pragma unroll
        for (int rg = 0; rg < 4; rg++) {
          #pragma unroll
          for (int j = 0; j < 4; j++) {
            float v = fmaxf(acc[rg][j] + bias, 0.f);
            mx = fmaxf(mx, v); sm += v;
          }
        }
        mx = fmaxf(mx, __shfl_xor(mx, 16)); sm += __shfl_xor(sm, 16);
        mx = fmaxf(mx, __shfl_xor(mx, 32)); sm += __shfl_xor(sm, 32);
        if (hi == 0 && c < DHID) {
          atomicMax(&maxb[g0 * DHID + c], __float_as_int(mx));
          atomicAdd(&sump[g0 * DHID + c], sm);
        }
      } else if (c < DHID) {
        #pragma unroll
        for (int rg = 0; rg < 4; rg++) {
          int rbase = m0 + rg * 16 + hi * 4;
          #pragma unroll
          for (int j = 0; j < 4; j++) {
            int row = rbase + j;
            if (row < N_NODES) {
              int g = batch[row];
              float v = fmaxf(acc[rg][j] + bias, 0.f);
              atomicMax(&maxb[g * DHID + c], __float_as_int(v));
              atomicAdd(&sump[g * DHID + c], v);
            }
          }
        }
      }
    }
  }
}

// ---------------- z = [maxp | meanp] ----------------
__global__ __launch_bounds__(256) void k_zprep(const int* __restrict__ maxb, const float* __restrict__ sump,
                                               const int* __restrict__ cnt, float* __restrict__ z) {
  int idx = blockIdx.x * 256 + threadIdx.x;
  if (idx >= NGRAPH * 2 * DHID) return;
  int g = idx / (2 * DHID), j = idx % (2 * DHID);
  int c = cnt[g];
  float v;
  if (j < DHID) v = (c > 0) ? __int_as_float(maxb[g * DHID + j]) : 0.f;
  else v = sump[g * DHID + (j - DHID)] / (float)max(c, 1);
  z[idx] = v;
}

// ---------------- MLP partial GEMM (f32, k-split, atomic accumulate) ----------------
template <int KTOT, int NTOT, int KC>
__global__ __launch_bounds__(256) void k_mlp(const float* __restrict__ Zin, const float* __restrict__ W,
                                             float* __restrict__ accout) {
  __shared__ float zt[128 * KC];
  int t = threadIdx.x;
  constexpr int NCH = NTOT / 64;
  int nc = blockIdx.x % NCH, kc = blockIdx.x / NCH;
  int k0 = kc * KC, n0 = nc * 64;
  for (int idx = t; idx < 128 * (KC / 4); idx += 256) {
    int r = idx / (KC / 4), c = idx % (KC / 4);
    *(f32x4*)&zt[r * KC + c * 4] = *(const f32x4*)&Zin[r * KTOT + k0 + c * 4];
  }
  __syncthreads();
  int nl = (t & 15) * 4, mg = t >> 4;
  f32x4 acc[8];
  #pragma unroll
  for (int mm = 0; mm < 8; mm++) acc[mm] = (f32x4){0.f, 0.f, 0.f, 0.f};
  #pragma unroll 4
  for (int k = 0; k < KC; k++) {
    f32x4 w4 = *(const f32x4*)&W[(k0 + k) * NTOT + n0 + nl];
    #pragma unroll
    for (int mm = 0; mm < 8; mm++) acc[mm] += zt[(mg * 8 + mm) * KC + k] * w4;
  }
  #pragma unroll
  for (int mm = 0; mm < 8; mm++)
    #pragma unroll
    for (int j = 0; j < 4; j++)
      atomicAdd(&accout[(mg * 8 + mm) * NTOT + n0 + nl + j], acc[mm][j]);
}

__global__ __launch_bounds__(256) void k_bias_relu(float* __restrict__ X, const float* __restrict__ b,
                                                   int NTOT, int total, int relu) {
  int i = blockIdx.x * 256 + threadIdx.x;
  if (i >= total) return;
  float v = X[i] + b[i % NTOT];
  X[i] = relu ? fmaxf(v, 0.f) : v;
}

// ---------------- launch ----------------
static constexpr size_t AL(size_t x) { return (x + 255) & ~(size_t)255; }

extern "C" void kernel_launch(void* const* d_in, const int* in_sizes, int n_in,
                              void* d_out, int out_size, void* d_ws, size_t ws_size,
                              hipStream_t stream) {
  const float* x   = (const float*)d_in[0];
  const int*  edge = (const int*)d_in[1];
  const int*  batch= (const int*)d_in[2];
  const float* W1  = (const float*)d_in[3];
  const float* b1  = (const float*)d_in[4];
  const float* W2  = (const float*)d_in[5];
  const float* b2  = (const float*)d_in[6];
  const float* Wg1 = (const float*)d_in[7];
  const float* bg1 = (const float*)d_in[8];
  const float* Wg2 = (const float*)d_in[9];
  const float* bg2 = (const float*)d_in[10];
  float* out = (float*)d_out;
  const int* src = edge;
  const int* dst = edge + N_EDGESC;

  size_t o = 0;
  size_t OFF_AGG = o;  o += AL((size_t)N_NODES * DIN * 4);
  size_t OFF_H1  = o;  o += AL((size_t)N_NODES * DIN * 4);
  size_t OFF_AGB = o;  o += AL((size_t)N_NODES * 96 * 2);
  size_t OFF_CSR = o;  o += AL((size_t)N_EDGESC * 4);
  size_t OFF_W2T = o;  o += AL((size_t)896 * 96 * 2);
  size_t OFF_W1H = o;  o += AL((size_t)96 * 96 * 2);
  size_t OFF_W1L = o;  o += AL((size_t)96 * 96 * 2);
  size_t OFF_RP  = o;  o += AL((size_t)(N_NODES + 1) * 4);
  size_t OFF_CUR = o;  o += AL((size_t)N_NODES * 4);
  size_t OFF_BS  = o;  o += AL(128 * 4);
  size_t OFF_BO  = o;  o += AL(128 * 4);
  size_t OFF_Z   = o;  o += AL((size_t)NGRAPH * 2 * DHID * 4);
  size_t OFF_DEG = o;  o += AL((size_t)N_NODES * 4);
  size_t OFF_MAX = o;  o += AL((size_t)NGRAPH * DHID * 4);
  size_t OFF_SUM = o;  o += AL((size_t)NGRAPH * DHID * 4);
  size_t OFF_CNT = o;  o += AL(NGRAPH * 4);
  size_t OFF_Z1  = o;  o += AL((size_t)NGRAPH * DF1 * 4);
  size_t TOTAL = o;
  size_t ZERO0 = OFF_DEG, ZEROB = TOTAL - OFF_DEG;
  if (ws_size < TOTAL) return;

  char* ws = (char*)d_ws;
  float* agg = (float*)(ws + OFF_AGG);
  float* h1  = (float*)(ws + OFF_H1);
  unsigned short* aggb = (unsigned short*)(ws + OFF_AGB);
  int* csr   = (int*)(ws + OFF_CSR);
  unsigned short* w2t = (unsigned short*)(ws + OFF_W2T);
  unsigned short* w1h = (unsigned short*)(ws + OFF_W1H);
  unsigned short* w1l = (unsigned short*)(ws + OFF_W1L);
  int* rowptr = (int*)(ws + OFF_RP);
  int* cursor = (int*)(ws + OFF_CUR);
  int* bsum  = (int*)(ws + OFF_BS);
  int* boff  = (int*)(ws + OFF_BO);
  float* z   = (float*)(ws + OFF_Z);
  int* deg   = (int*)(ws + OFF_DEG);
  int* maxb  = (int*)(ws + OFF_MAX);
  float* sump= (float*)(ws + OFF_SUM);
  int* cnt   = (int*)(ws + OFF_CNT);
  float* z1  = (float*)(ws + OFF_Z1);

  hipMemsetAsync(ws + ZERO0, 0, ZEROB, stream);
  hipMemsetAsync(d_out, 0, (size_t)out_size * 4, stream);

  k_w2t<<<(896 * 96 + 255) / 256, 256, 0, stream>>>(W2, w2t);
  k_w1t<<<(96 * 96 + 255) / 256, 256, 0, stream>>>(W1, w1h, w1l);
  k_deg<<<N_EDGESC / 256, 256, 0, stream>>>(dst, deg);
  k_scan1<<<SBLOCKS, 256, 0, stream>>>(deg, bsum);
  k_scan2<<<1, 128, 0, stream>>>(bsum, boff);
  k_scan3<<<SBLOCKS, 256, 0, stream>>>(deg, boff, rowptr, cursor);
  k_fill<<<N_EDGESC / 256, 256, 0, stream>>>(src, dst, cursor, csr);
  k_counts<<<(N_NODES + 2047) / 2048, 256, 0, stream>>>(batch, cnt);

  k_agg<false><<<(N_NODES + 7) / 8, 256, 0, stream>>>(x, rowptr, csr, agg);
  k_conv1m<<<(N_NODES + 63) / 64, 256, 0, stream>>>(agg, w1h, w1l, b1, h1);
  k_agg<true><<<(N_NODES + 7) / 8, 256, 0, stream>>>(h1, rowptr, csr, aggb);
  k_conv2pool2<<<(N_NODES + 63) / 64, 256, 0, stream>>>(aggb, w2t, b2, batch, maxb, sump);

  k_zprep<<<(NGRAPH * 2 * DHID + 255) / 256, 256, 0, stream>>>(maxb, sump, cnt, z);
  k_mlp<2 * DHID, DF1, 120><<<(DF1 / 64) * (2 * DHID / 120), 256, 0, stream>>>(z, Wg1, z1);
  k_bias_relu<<<(NGRAPH * DF1 + 255) / 256, 256, 0, stream>>>(z1, bg1, DF1, NGRAPH * DF1, 1);
  k_mlp<DF1, DOUTC, 64><<<(DOUTC / 64) * (DF1 / 64), 256, 0, stream>>>(z1, Wg2, out);
  k_bias_relu<<<(NGRAPH * DOUTC + 255) / 256, 256, 0, stream>>>(out, bg2, DOUTC, NGRAPH * DOUTC, 0);
}

// Round 4
// 390.522 us; speedup vs baseline: 1.4684x; 1.4684x over previous
//
#include <hip/hip_runtime.h>

#define N_NODES 100000
#define N_EDGESC 800000
#define NGRAPH 128
#define DIN 84
#define DHID 840
#define DF1 1024
#define DOUTC 384
#define PBLK 391   // ceil(N_NODES/256)

typedef __attribute__((ext_vector_type(4))) float f32x4;
typedef __attribute__((ext_vector_type(8))) short bf16x8;

__device__ __forceinline__ unsigned short f2bf(float f) {
  union { float f; unsigned int u; } v; v.f = f;
  unsigned int r = v.u + 0x7FFFu + ((v.u >> 16) & 1u);
  return (unsigned short)(r >> 16);
}
__device__ __forceinline__ float bf2f(unsigned short h) {
  union { unsigned int u; float f; } v; v.u = ((unsigned int)h) << 16;
  return v.f;
}

// ---------------- CSR build ----------------
__global__ __launch_bounds__(256) void k_deg(const int* __restrict__ dst, int* __restrict__ deg) {
  int e = blockIdx.x * 256 + threadIdx.x;
  if (e >= N_EDGESC) return;
  atomicAdd(&deg[dst[e]], 1);
}

#define SCHUNK 1024
#define SBLOCKS 98   // ceil(100000/1024)

__global__ __launch_bounds__(256) void k_scan1(const int* __restrict__ deg, int* __restrict__ bsum) {
  __shared__ int sd[256];
  int b = blockIdx.x, t = threadIdx.x;
  int base = b * SCHUNK + t * 4;
  int s = 0;
  for (int j = 0; j < 4; j++) { int i = base + j; if (i < N_NODES) s += deg[i]; }
  sd[t] = s; __syncthreads();
  for (int off = 128; off > 0; off >>= 1) {
    if (t < off) sd[t] += sd[t + off];
    __syncthreads();
  }
  if (t == 0) bsum[b] = sd[0];
}

__global__ __launch_bounds__(128) void k_scan2(const int* __restrict__ bsum, int* __restrict__ boff) {
  __shared__ int sd[128];
  int t = threadIdx.x;
  int v = (t < SBLOCKS) ? bsum[t] : 0;
  sd[t] = v; __syncthreads();
  for (int off = 1; off < 128; off <<= 1) {
    int add = (t >= off) ? sd[t - off] : 0;
    __syncthreads();
    sd[t] += add;
    __syncthreads();
  }
  if (t < SBLOCKS) boff[t] = sd[t] - v;
}

__global__ __launch_bounds__(256) void k_scan3(const int* __restrict__ deg, const int* __restrict__ boff,
                                               int* __restrict__ rowptr, int* __restrict__ cursor) {
  __shared__ int sd[256];
  int b = blockIdx.x, t = threadIdx.x;
  int base = b * SCHUNK + t * 4;
  int v[4]; int s = 0;
  for (int j = 0; j < 4; j++) { int i = base + j; v[j] = (i < N_NODES) ? deg[i] : 0; s += v[j]; }
  sd[t] = s; __syncthreads();
  for (int off = 1; off < 256; off <<= 1) {
    int add = (t >= off) ? sd[t - off] : 0;
    __syncthreads();
    sd[t] += add;
    __syncthreads();
  }
  int run = sd[t] - s + boff[b];
  for (int j = 0; j < 4; j++) {
    int i = base + j;
    if (i < N_NODES) { rowptr[i] = run; cursor[i] = run; }
    run += v[j];
  }
  if (b == 0 && t == 0) rowptr[N_NODES] = N_EDGESC;
}

__global__ __launch_bounds__(256) void k_fill(const int* __restrict__ src, const int* __restrict__ dst,
                                              int* __restrict__ cursor, int* __restrict__ csr) {
  int e = blockIdx.x * 256 + threadIdx.x;
  if (e >= N_EDGESC) return;
  int d = dst[e];
  int pos = atomicAdd(&cursor[d], 1);
  csr[pos] = src[e];
}

// ---------------- per-graph node counts ----------------
__global__ __launch_bounds__(256) void k_counts(const int* __restrict__ batch, int* __restrict__ cnt) {
  __shared__ int h[NGRAPH];
  int t = threadIdx.x;
  if (t < NGRAPH) h[t] = 0;
  __syncthreads();
  int base = blockIdx.x * 2048;
  for (int j = 0; j < 8; j++) {
    int i = base + j * 256 + t;
    if (i < N_NODES) atomicAdd(&h[batch[i]], 1);
  }
  __syncthreads();
  if (t < NGRAPH && h[t] > 0) atomicAdd(&cnt[t], h[t]);
}

// ---------------- aggregation: out[i] = x[i] + sum_{e in in(i)} x[src_e] ----------------
template <bool BF16OUT>
__global__ __launch_bounds__(256) void k_agg(const float* __restrict__ xin, const int* __restrict__ rowptr,
                                             const int* __restrict__ csr, void* __restrict__ outv) {
  int node = blockIdx.x * 8 + (threadIdx.x >> 5);
  int lane = threadIdx.x & 31;
  if (node >= N_NODES) return;
  int r0 = rowptr[node], r1 = rowptr[node + 1];
  const f32x4* x4 = (const f32x4*)xin;
  bool act = lane < 21;
  f32x4 a = {0.f, 0.f, 0.f, 0.f};
  if (act) a = x4[node * 21 + lane];
  int e = r0;
  for (; e + 4 <= r1; e += 4) {
    int s0 = csr[e], s1 = csr[e + 1], s2 = csr[e + 2], s3 = csr[e + 3];
    if (act) {
      f32x4 v0 = x4[s0 * 21 + lane];
      f32x4 v1 = x4[s1 * 21 + lane];
      f32x4 v2 = x4[s2 * 21 + lane];
      f32x4 v3 = x4[s3 * 21 + lane];
      a += (v0 + v1) + (v2 + v3);
    }
  }
  for (; e < r1; e++) {
    int s = csr[e];
    if (act) a += x4[s * 21 + lane];
  }
  if (BF16OUT) {
    unsigned short* ob = (unsigned short*)outv;
    if (lane < 24) {
      uint2 p;
      if (act) {
        p.x = (unsigned int)f2bf(a.x) | ((unsigned int)f2bf(a.y) << 16);
        p.y = (unsigned int)f2bf(a.z) | ((unsigned int)f2bf(a.w) << 16);
      } else {
        p.x = 0u; p.y = 0u;   // zero K-pad cols 84..95
      }
      *(uint2*)&ob[node * 96 + lane * 4] = p;
    }
  } else {
    if (act) ((f32x4*)outv)[node * 21 + lane] = a;
  }
}

// ---------------- W1^T split hi/lo bf16, padded [96][96] ----------------
__global__ __launch_bounds__(256) void k_w1t(const float* __restrict__ W1, unsigned short* __restrict__ w1h,
                                             unsigned short* __restrict__ w1l) {
  int idx = blockIdx.x * 256 + threadIdx.x;
  if (idx >= 96 * 96) return;
  int n = idx / 96, k = idx % 96;
  float v = (n < DIN && k < DIN) ? W1[k * DIN + n] : 0.f;
  unsigned short h = f2bf(v);
  w1h[idx] = h;
  w1l[idx] = f2bf(v - bf2f(h));
}

// ---------------- conv1 via MFMA, split-bf16 ----------------
__global__ __launch_bounds__(256) void k_conv1m(const float* __restrict__ agg,
                                                const unsigned short* __restrict__ w1h,
                                                const unsigned short* __restrict__ w1l,
                                                const float* __restrict__ b1, float* __restrict__ h1) {
  constexpr int LDA = 104;
  __shared__ __align__(16) unsigned short Ah[64 * LDA];
  __shared__ __align__(16) unsigned short Al[64 * LDA];
  int t = threadIdx.x;
  int m0 = blockIdx.x * 64;

  for (int idx = t; idx < 64 * 21; idx += 256) {
    int r = idx / 21, c = idx - r * 21;
    int row = m0 + r;
    f32x4 v = {0.f, 0.f, 0.f, 0.f};
    if (row < N_NODES) v = *(const f32x4*)&agg[row * DIN + c * 4];
    unsigned short h0 = f2bf(v.x), h1_ = f2bf(v.y), h2_ = f2bf(v.z), h3_ = f2bf(v.w);
    unsigned short l0 = f2bf(v.x - bf2f(h0)), l1 = f2bf(v.y - bf2f(h1_));
    unsigned short l2 = f2bf(v.z - bf2f(h2_)), l3 = f2bf(v.w - bf2f(h3_));
    unsigned int* ph = (unsigned int*)&Ah[r * LDA + c * 4];
    ph[0] = (unsigned int)h0 | ((unsigned int)h1_ << 16);
    ph[1] = (unsigned int)h2_ | ((unsigned int)h3_ << 16);
    unsigned int* pl = (unsigned int*)&Al[r * LDA + c * 4];
    pl[0] = (unsigned int)l0 | ((unsigned int)l1 << 16);
    pl[1] = (unsigned int)l2 | ((unsigned int)l3 << 16);
  }
  for (int idx = t; idx < 64 * 6; idx += 256) {
    int r = idx / 6, c = idx - r * 6;
    ((unsigned int*)&Ah[r * LDA + 84])[c] = 0;
    ((unsigned int*)&Al[r * LDA + 84])[c] = 0;
  }
  __syncthreads();

  int w = t >> 6, l = t & 63;
  int lr = l & 15, lk = (l >> 4) * 8;
  bf16x8 ah[3], al[3];
  #pragma unroll
  for (int kk = 0; kk < 3; kk++) {
    ah[kk] = *(bf16x8*)&Ah[(w * 16 + lr) * LDA + lk + kk * 32];
    al[kk] = *(bf16x8*)&Al[(w * 16 + lr) * LDA + lk + kk * 32];
  }

  #pragma unroll
  for (int nt = 0; nt < 6; nt++) {
    f32x4 acc = {0.f, 0.f, 0.f, 0.f};
    #pragma unroll
    for (int kk = 0; kk < 3; kk++) {
      bf16x8 bh = *(const bf16x8*)&w1h[(nt * 16 + lr) * 96 + lk + kk * 32];
      bf16x8 bl = *(const bf16x8*)&w1l[(nt * 16 + lr) * 96 + lk + kk * 32];
      acc = __builtin_amdgcn_mfma_f32_16x16x32_bf16(ah[kk], bh, acc, 0, 0, 0);
      acc = __builtin_amdgcn_mfma_f32_16x16x32_bf16(al[kk], bh, acc, 0, 0, 0);
      acc = __builtin_amdgcn_mfma_f32_16x16x32_bf16(ah[kk], bl, acc, 0, 0, 0);
    }
    int col = nt * 16 + lr;
    if (col < DIN) {
      float bias = b1[col];
      int rbase = m0 + w * 16 + (l >> 4) * 4;
      #pragma unroll
      for (int j = 0; j < 4; j++) {
        if (rbase + j < N_NODES)
          h1[(rbase + j) * DIN + col] = fmaxf(acc[j] + bias, 0.f);
      }
    }
  }
}

// ---------------- W2^T in bf16, padded [896][96] ----------------
__global__ __launch_bounds__(256) void k_w2t(const float* __restrict__ W2, unsigned short* __restrict__ w2t) {
  int idx = blockIdx.x * 256 + threadIdx.x;
  if (idx >= 896 * 96) return;
  int n = idx / 96, k = idx % 96;
  float v = (n < DHID && k < DIN) ? W2[k * DHID + n] : 0.f;
  w2t[idx] = f2bf(v);
}

// ---------------- conv2 + pooling, stage 1: per-block partials, no global atomics --------
// Block = 256 rows x 4 waves; wave w owns rows m0+w*64..+63 (A fragments in registers).
// batch sorted => block spans <=2 graphs (seg0 = batch[m0], seg1 = batch[m0+255]); LDS
// atomics combine the 4 waves; plain stores flush per-block partials. Middle segments
// (pathological, graph < 256 nodes) fall back to global atomics into maxb/sump.
__global__ __launch_bounds__(256) void k_conv2pool3(const unsigned short* __restrict__ aggb,
                                                    const unsigned short* __restrict__ w2t,
                                                    const float* __restrict__ b2,
                                                    const int* __restrict__ batch,
                                                    int* __restrict__ pm0, float* __restrict__ ps0,
                                                    int* __restrict__ pm1, float* __restrict__ ps1,
                                                    int* __restrict__ blkg,
                                                    int* __restrict__ maxb, float* __restrict__ sump) {
  __shared__ int   smax0[DHID]; __shared__ float ssum0[DHID];
  __shared__ int   smax1[DHID]; __shared__ float ssum1[DHID];
  int t = threadIdx.x;
  int w = t >> 6, l = t & 63;
  int b = blockIdx.x;
  int m0 = b * 256;
  int r0 = m0 + w * 64;
  int lr = l & 15, hi = l >> 4, lk = hi * 8;

  for (int i = t; i < DHID; i += 256) { smax0[i] = 0; ssum0[i] = 0.f; smax1[i] = 0; ssum1[i] = 0.f; }

  // A fragments: 4 row-groups x 3 k-chunks
  bf16x8 afr[4][3];
  #pragma unroll
  for (int rg = 0; rg < 4; rg++) {
    int row = r0 + rg * 16 + lr;
    #pragma unroll
    for (int kk = 0; kk < 3; kk++) {
      bf16x8 v = {0, 0, 0, 0, 0, 0, 0, 0};
      if (row < N_NODES) v = *(const bf16x8*)&aggb[row * 96 + lk + kk * 32];
      afr[rg][kk] = v;
    }
  }
  // per-lane row graphs (C/D rows: r0 + rg*16 + hi*4 + j)
  int grow[4][4];
  #pragma unroll
  for (int rg = 0; rg < 4; rg++)
    #pragma unroll
    for (int j = 0; j < 4; j++) {
      int row = r0 + rg * 16 + hi * 4 + j;
      grow[rg][j] = (row < N_NODES) ? batch[row] : -1;
    }

  int g0 = batch[m0];
  int g1 = batch[min(m0 + 255, N_NODES - 1)];
  __syncthreads();

  for (int nc = 0; nc < 14; nc++) {
    #pragma unroll
    for (int nt = 0; nt < 4; nt++) {
      int c = nc * 64 + nt * 16 + lr;
      const unsigned short* bp = &w2t[(nc * 64 + nt * 16 + lr) * 96 + lk];
      bf16x8 b0v = *(const bf16x8*)(bp);
      bf16x8 b1v = *(const bf16x8*)(bp + 32);
      bf16x8 b2v = *(const bf16x8*)(bp + 64);
      float bias = (c < DHID) ? b2[c] : 0.f;
      float mx0 = 0.f, sm0 = 0.f, mx1 = 0.f, sm1 = 0.f;
      float vv[4][4];
      #pragma unroll
      for (int rg = 0; rg < 4; rg++) {
        f32x4 a_ = {0.f, 0.f, 0.f, 0.f};
        a_ = __builtin_amdgcn_mfma_f32_16x16x32_bf16(afr[rg][0], b0v, a_, 0, 0, 0);
        a_ = __builtin_amdgcn_mfma_f32_16x16x32_bf16(afr[rg][1], b1v, a_, 0, 0, 0);
        a_ = __builtin_amdgcn_mfma_f32_16x16x32_bf16(afr[rg][2], b2v, a_, 0, 0, 0);
        #pragma unroll
        for (int j = 0; j < 4; j++) {
          float v = fmaxf(a_[j] + bias, 0.f);
          vv[rg][j] = v;
          if (grow[rg][j] == g0) { mx0 = fmaxf(mx0, v); sm0 += v; }
          if (grow[rg][j] == g1) { mx1 = fmaxf(mx1, v); sm1 += v; }
        }
      }
      mx0 = fmaxf(mx0, __shfl_xor(mx0, 16)); sm0 += __shfl_xor(sm0, 16);
      mx0 = fmaxf(mx0, __shfl_xor(mx0, 32)); sm0 += __shfl_xor(sm0, 32);
      mx1 = fmaxf(mx1, __shfl_xor(mx1, 16)); sm1 += __shfl_xor(sm1, 16);
      mx1 = fmaxf(mx1, __shfl_xor(mx1, 32)); sm1 += __shfl_xor(sm1, 32);
      if (hi == 0 && c < DHID) {
        atomicMax(&smax0[c], __float_as_int(mx0));
        atomicAdd(&ssum0[c], sm0);
        atomicMax(&smax1[c], __float_as_int(mx1));
        atomicAdd(&ssum1[c], sm1);
      }
      if (g1 - g0 >= 2) {  // pathological middle segments
        for (int g = g0 + 1; g < g1; g++) {
          float mx = 0.f, sm = 0.f;
          #pragma unroll
          for (int rg = 0; rg < 4; rg++)
            #pragma unroll
            for (int j = 0; j < 4; j++)
              if (grow[rg][j] == g) { mx = fmaxf(mx, vv[rg][j]); sm += vv[rg][j]; }
          mx = fmaxf(mx, __shfl_xor(mx, 16)); sm += __shfl_xor(sm, 16);
          mx = fmaxf(mx, __shfl_xor(mx, 32)); sm += __shfl_xor(sm, 32);
          if (hi == 0 && c < DHID) {
            atomicMax(&maxb[g * DHID + c], __float_as_int(mx));
            atomicAdd(&sump[g * DHID + c], sm);
          }
        }
      }
    }
  }
  __syncthreads();
  for (int i = t; i < DHID; i += 256) {
    pm0[b * DHID + i] = smax0[i];
    ps0[b * DHID + i] = ssum0[i];
    pm1[b * DHID + i] = smax1[i];
    ps1[b * DHID + i] = ssum1[i];
  }
  if (t == 0) { blkg[b * 2] = g0; blkg[b * 2 + 1] = g1; }
}

// ---------------- pooling stage 2: merge partials, write z = [maxp | meanp] --------------
__global__ __launch_bounds__(256) void k_pool2(const int* __restrict__ pm0, const float* __restrict__ ps0,
                                               const int* __restrict__ pm1, const float* __restrict__ ps1,
                                               const int* __restrict__ blkg, const int* __restrict__ cnt,
                                               const int* __restrict__ maxb, const float* __restrict__ sump,
                                               float* __restrict__ z) {
  __shared__ int sstart[NGRAPH];
  int g = blockIdx.x, t = threadIdx.x;
  if (t == 0) {
    int s = 0;
    for (int i = 0; i < NGRAPH; i++) { sstart[i] = s; s += cnt[i]; }
  }
  __syncthreads();
  int c0 = cnt[g];
  int ns = sstart[g], ne = ns + c0;
  int b0 = ns / 256, b1 = (c0 > 0) ? (ne - 1) / 256 : b0 - 1;
  for (int c = t; c < DHID; c += 256) {
    float mx = __int_as_float(maxb[g * DHID + c]);  // >= 0; fallback buffer
    float sm = sump[g * DHID + c];
    for (int b = b0; b <= b1; b++) {
      int gg0 = blkg[2 * b], gg1 = blkg[2 * b + 1];
      if (gg0 == g)      { mx = fmaxf(mx, __int_as_float(pm0[b * DHID + c])); sm += ps0[b * DHID + c]; }
      else if (gg1 == g) { mx = fmaxf(mx, __int_as_float(pm1[b * DHID + c])); sm += ps1[b * DHID + c]; }
    }
    z[g * (2 * DHID) + c] = (c0 > 0) ? mx : 0.f;
    z[g * (2 * DHID) + DHID + c] = sm / (float)max(c0, 1);
  }
}

// ---------------- MLP partial GEMM (f32, k-split, atomic accumulate) ----------------
template <int KTOT, int NTOT, int KC>
__global__ __launch_bounds__(256) void k_mlp(const float* __restrict__ Zin, const float* __restrict__ W,
                                             float* __restrict__ accout) {
  __shared__ float zt[128 * KC];
  int t = threadIdx.x;
  constexpr int NCH = NTOT / 64;
  int nc = blockIdx.x % NCH, kc = blockIdx.x / NCH;
  int k0 = kc * KC, n0 = nc * 64;
  for (int idx = t; idx < 128 * (KC / 4); idx += 256) {
    int r = idx / (KC / 4), c = idx % (KC / 4);
    *(f32x4*)&zt[r * KC + c * 4] = *(const f32x4*)&Zin[r * KTOT + k0 + c * 4];
  }
  __syncthreads();
  int nl = (t & 15) * 4, mg = t >> 4;
  f32x4 acc[8];
  #pragma unroll
  for (int mm = 0; mm < 8; mm++) acc[mm] = (f32x4){0.f, 0.f, 0.f, 0.f};
  #pragma unroll 4
  for (int k = 0; k < KC; k++) {
    f32x4 w4 = *(const f32x4*)&W[(k0 + k) * NTOT + n0 + nl];
    #pragma unroll
    for (int mm = 0; mm < 8; mm++) acc[mm] += zt[(mg * 8 + mm) * KC + k] * w4;
  }
  #pragma unroll
  for (int mm = 0; mm < 8; mm++)
    #pragma unroll
    for (int j = 0; j < 4; j++)
      atomicAdd(&accout[(mg * 8 + mm) * NTOT + n0 + nl + j], acc[mm][j]);
}

__global__ __launch_bounds__(256) void k_bias_relu(float* __restrict__ X, const float* __restrict__ b,
                                                   int NTOT, int total, int relu) {
  int i = blockIdx.x * 256 + threadIdx.x;
  if (i >= total) return;
  float v = X[i] + b[i % NTOT];
  X[i] = relu ? fmaxf(v, 0.f) : v;
}

// ---------------- launch ----------------
static constexpr size_t AL(size_t x) { return (x + 255) & ~(size_t)255; }

extern "C" void kernel_launch(void* const* d_in, const int* in_sizes, int n_in,
                              void* d_out, int out_size, void* d_ws, size_t ws_size,
                              hipStream_t stream) {
  const float* x   = (const float*)d_in[0];
  const int*  edge = (const int*)d_in[1];
  const int*  batch= (const int*)d_in[2];
  const float* W1  = (const float*)d_in[3];
  const float* b1  = (const float*)d_in[4];
  const float* W2  = (const float*)d_in[5];
  const float* b2  = (const float*)d_in[6];
  const float* Wg1 = (const float*)d_in[7];
  const float* bg1 = (const float*)d_in[8];
  const float* Wg2 = (const float*)d_in[9];
  const float* bg2 = (const float*)d_in[10];
  float* out = (float*)d_out;
  const int* src = edge;
  const int* dst = edge + N_EDGESC;

  size_t o = 0;
  size_t OFF_AGG = o;  o += AL((size_t)N_NODES * DIN * 4);   // reused for pooling partials
  size_t OFF_H1  = o;  o += AL((size_t)N_NODES * DIN * 4);
  size_t OFF_AGB = o;  o += AL((size_t)N_NODES * 96 * 2);
  size_t OFF_CSR = o;  o += AL((size_t)N_EDGESC * 4);
  size_t OFF_W2T = o;  o += AL((size_t)896 * 96 * 2);
  size_t OFF_W1H = o;  o += AL((size_t)96 * 96 * 2);
  size_t OFF_W1L = o;  o += AL((size_t)96 * 96 * 2);
  size_t OFF_RP  = o;  o += AL((size_t)(N_NODES + 1) * 4);
  size_t OFF_CUR = o;  o += AL((size_t)N_NODES * 4);
  size_t OFF_BS  = o;  o += AL(128 * 4);
  size_t OFF_BO  = o;  o += AL(128 * 4);
  size_t OFF_Z   = o;  o += AL((size_t)NGRAPH * 2 * DHID * 4);
  size_t OFF_DEG = o;  o += AL((size_t)N_NODES * 4);
  size_t OFF_MAX = o;  o += AL((size_t)NGRAPH * DHID * 4);
  size_t OFF_SUM = o;  o += AL((size_t)NGRAPH * DHID * 4);
  size_t OFF_CNT = o;  o += AL(NGRAPH * 4);
  size_t OFF_Z1  = o;  o += AL((size_t)NGRAPH * DF1 * 4);
  size_t TOTAL = o;
  size_t ZERO0 = OFF_DEG, ZEROB = TOTAL - OFF_DEG;
  if (ws_size < TOTAL) return;

  // pooling partials alias the agg region (agg's last reader, k_conv1m, runs before stage 1)
  size_t PB = AL((size_t)PBLK * DHID * 4);
  size_t OFF_PM0 = OFF_AGG;
  size_t OFF_PS0 = OFF_AGG + PB;
  size_t OFF_PM1 = OFF_AGG + 2 * PB;
  size_t OFF_PS1 = OFF_AGG + 3 * PB;
  size_t OFF_BLG = OFF_AGG + 4 * PB;   // 4*PB + 3KB << 33.6MB

  char* ws = (char*)d_ws;
  float* agg = (float*)(ws + OFF_AGG);
  float* h1  = (float*)(ws + OFF_H1);
  unsigned short* aggb = (unsigned short*)(ws + OFF_AGB);
  int* csr   = (int*)(ws + OFF_CSR);
  unsigned short* w2t = (unsigned short*)(ws + OFF_W2T);
  unsigned short* w1h = (unsigned short*)(ws + OFF_W1H);
  unsigned short* w1l = (unsigned short*)(ws + OFF_W1L);
  int* rowptr = (int*)(ws + OFF_RP);
  int* cursor = (int*)(ws + OFF_CUR);
  int* bsum  = (int*)(ws + OFF_BS);
  int* boff  = (int*)(ws + OFF_BO);
  float* z   = (float*)(ws + OFF_Z);
  int* deg   = (int*)(ws + OFF_DEG);
  int* maxb  = (int*)(ws + OFF_MAX);
  float* sump= (float*)(ws + OFF_SUM);
  int* cnt   = (int*)(ws + OFF_CNT);
  float* z1  = (float*)(ws + OFF_Z1);
  int* pm0   = (int*)(ws + OFF_PM0);
  float* ps0 = (float*)(ws + OFF_PS0);
  int* pm1   = (int*)(ws + OFF_PM1);
  float* ps1 = (float*)(ws + OFF_PS1);
  int* blkg  = (int*)(ws + OFF_BLG);

  hipMemsetAsync(ws + ZERO0, 0, ZEROB, stream);
  hipMemsetAsync(d_out, 0, (size_t)out_size * 4, stream);

  k_w2t<<<(896 * 96 + 255) / 256, 256, 0, stream>>>(W2, w2t);
  k_w1t<<<(96 * 96 + 255) / 256, 256, 0, stream>>>(W1, w1h, w1l);
  k_deg<<<N_EDGESC / 256, 256, 0, stream>>>(dst, deg);
  k_scan1<<<SBLOCKS, 256, 0, stream>>>(deg, bsum);
  k_scan2<<<1, 128, 0, stream>>>(bsum, boff);
  k_scan3<<<SBLOCKS, 256, 0, stream>>>(deg, boff, rowptr, cursor);
  k_fill<<<N_EDGESC / 256, 256, 0, stream>>>(src, dst, cursor, csr);
  k_counts<<<(N_NODES + 2047) / 2048, 256, 0, stream>>>(batch, cnt);

  k_agg<false><<<(N_NODES + 7) / 8, 256, 0, stream>>>(x, rowptr, csr, agg);
  k_conv1m<<<(N_NODES + 63) / 64, 256, 0, stream>>>(agg, w1h, w1l, b1, h1);
  k_agg<true><<<(N_NODES + 7) / 8, 256, 0, stream>>>(h1, rowptr, csr, aggb);
  k_conv2pool3<<<PBLK, 256, 0, stream>>>(aggb, w2t, b2, batch, pm0, ps0, pm1, ps1, blkg, maxb, sump);
  k_pool2<<<NGRAPH, 256, 0, stream>>>(pm0, ps0, pm1, ps1, blkg, cnt, maxb, sump, z);

  k_mlp<2 * DHID, DF1, 120><<<(DF1 / 64) * (2 * DHID / 120), 256, 0, stream>>>(z, Wg1, z1);
  k_bias_relu<<<(NGRAPH * DF1 + 255) / 256, 256, 0, stream>>>(z1, bg1, DF1, NGRAPH * DF1, 1);
  k_mlp<DF1, DOUTC, 64><<<(DOUTC / 64) * (DF1 / 64), 256, 0, stream>>>(z1, Wg2, out);
  k_bias_relu<<<(NGRAPH * DOUTC + 255) / 256, 256, 0, stream>>>(out, bg2, DOUTC, NGRAPH * DOUTC, 0);
}

// Round 5
// 373.399 us; speedup vs baseline: 1.5358x; 1.0459x over previous
//
#include <hip/hip_runtime.h>

#define N_NODES 100000
#define N_EDGESC 800000
#define NGRAPH 128
#define DIN 84
#define DHID 840
#define DF1 1024
#define DOUTC 384
#define PBLK2 782   // ceil(N_NODES/128)

typedef __attribute__((ext_vector_type(4))) float f32x4;
typedef __attribute__((ext_vector_type(8))) short bf16x8;

__device__ __forceinline__ unsigned short f2bf(float f) {
  union { float f; unsigned int u; } v; v.f = f;
  unsigned int r = v.u + 0x7FFFu + ((v.u >> 16) & 1u);
  return (unsigned short)(r >> 16);
}
__device__ __forceinline__ float bf2f(unsigned short h) {
  union { unsigned int u; float f; } v; v.u = ((unsigned int)h) << 16;
  return v.f;
}

// ---------------- CSR build ----------------
__global__ __launch_bounds__(256) void k_deg(const int* __restrict__ dst, int* __restrict__ deg) {
  int e = blockIdx.x * 256 + threadIdx.x;
  if (e >= N_EDGESC) return;
  atomicAdd(&deg[dst[e]], 1);
}

#define SCHUNK 1024
#define SBLOCKS 98   // ceil(100000/1024)

__global__ __launch_bounds__(256) void k_scan1(const int* __restrict__ deg, int* __restrict__ bsum) {
  __shared__ int sd[256];
  int b = blockIdx.x, t = threadIdx.x;
  int base = b * SCHUNK + t * 4;
  int s = 0;
  for (int j = 0; j < 4; j++) { int i = base + j; if (i < N_NODES) s += deg[i]; }
  sd[t] = s; __syncthreads();
  for (int off = 128; off > 0; off >>= 1) {
    if (t < off) sd[t] += sd[t + off];
    __syncthreads();
  }
  if (t == 0) bsum[b] = sd[0];
}

__global__ __launch_bounds__(128) void k_scan2(const int* __restrict__ bsum, int* __restrict__ boff) {
  __shared__ int sd[128];
  int t = threadIdx.x;
  int v = (t < SBLOCKS) ? bsum[t] : 0;
  sd[t] = v; __syncthreads();
  for (int off = 1; off < 128; off <<= 1) {
    int add = (t >= off) ? sd[t - off] : 0;
    __syncthreads();
    sd[t] += add;
    __syncthreads();
  }
  if (t < SBLOCKS) boff[t] = sd[t] - v;
}

__global__ __launch_bounds__(256) void k_scan3(const int* __restrict__ deg, const int* __restrict__ boff,
                                               int* __restrict__ rowptr, int* __restrict__ cursor) {
  __shared__ int sd[256];
  int b = blockIdx.x, t = threadIdx.x;
  int base = b * SCHUNK + t * 4;
  int v[4]; int s = 0;
  for (int j = 0; j < 4; j++) { int i = base + j; v[j] = (i < N_NODES) ? deg[i] : 0; s += v[j]; }
  sd[t] = s; __syncthreads();
  for (int off = 1; off < 256; off <<= 1) {
    int add = (t >= off) ? sd[t - off] : 0;
    __syncthreads();
    sd[t] += add;
    __syncthreads();
  }
  int run = sd[t] - s + boff[b];
  for (int j = 0; j < 4; j++) {
    int i = base + j;
    if (i < N_NODES) { rowptr[i] = run; cursor[i] = run; }
    run += v[j];
  }
  if (b == 0 && t == 0) rowptr[N_NODES] = N_EDGESC;
}

__global__ __launch_bounds__(256) void k_fill(const int* __restrict__ src, const int* __restrict__ dst,
                                              int* __restrict__ cursor, int* __restrict__ csr) {
  int e = blockIdx.x * 256 + threadIdx.x;
  if (e >= N_EDGESC) return;
  int d = dst[e];
  int pos = atomicAdd(&cursor[d], 1);
  csr[pos] = src[e];
}

// ---------------- per-graph node counts ----------------
__global__ __launch_bounds__(256) void k_counts(const int* __restrict__ batch, int* __restrict__ cnt) {
  __shared__ int h[NGRAPH];
  int t = threadIdx.x;
  if (t < NGRAPH) h[t] = 0;
  __syncthreads();
  int base = blockIdx.x * 2048;
  for (int j = 0; j < 8; j++) {
    int i = base + j * 256 + t;
    if (i < N_NODES) atomicAdd(&h[batch[i]], 1);
  }
  __syncthreads();
  if (t < NGRAPH && h[t] > 0) atomicAdd(&cnt[t], h[t]);
}

// ---------------- agg1: f32 in, f32 out (stride 84) ----------------
__global__ __launch_bounds__(256) void k_agg1(const float* __restrict__ xin, const int* __restrict__ rowptr,
                                              const int* __restrict__ csr, float* __restrict__ out) {
  int node = blockIdx.x * 8 + (threadIdx.x >> 5);
  int lane = threadIdx.x & 31;
  if (node >= N_NODES) return;
  int r0 = rowptr[node], r1 = rowptr[node + 1];
  const f32x4* x4 = (const f32x4*)xin;
  bool act = lane < 21;
  f32x4 a = {0.f, 0.f, 0.f, 0.f};
  if (act) a = x4[node * 21 + lane];
  int e = r0;
  for (; e + 4 <= r1; e += 4) {
    int s0 = csr[e], s1 = csr[e + 1], s2 = csr[e + 2], s3 = csr[e + 3];
    if (act) {
      f32x4 v0 = x4[s0 * 21 + lane];
      f32x4 v1 = x4[s1 * 21 + lane];
      f32x4 v2 = x4[s2 * 21 + lane];
      f32x4 v3 = x4[s3 * 21 + lane];
      a += (v0 + v1) + (v2 + v3);
    }
  }
  for (; e < r1; e++) {
    int s = csr[e];
    if (act) a += x4[s * 21 + lane];
  }
  if (act) ((f32x4*)out)[node * 21 + lane] = a;
}

// ---------------- agg2: bf16 in (stride 84), bf16 out (stride 96, zero-pad) ----------------
// Safe in bf16: h1 is post-ReLU (>=0) so the edge-sum has no cancellation; input rounding
// adds at most the same relative error as the output rounding we already do.
__device__ __forceinline__ f32x4 bfq(uint2 p) {
  f32x4 r;
  r.x = bf2f((unsigned short)(p.x & 0xffff)); r.y = bf2f((unsigned short)(p.x >> 16));
  r.z = bf2f((unsigned short)(p.y & 0xffff)); r.w = bf2f((unsigned short)(p.y >> 16));
  return r;
}
__global__ __launch_bounds__(256) void k_agg2(const unsigned short* __restrict__ h1b, const int* __restrict__ rowptr,
                                              const int* __restrict__ csr, unsigned short* __restrict__ out) {
  int node = blockIdx.x * 8 + (threadIdx.x >> 5);
  int lane = threadIdx.x & 31;
  if (node >= N_NODES) return;
  int r0 = rowptr[node], r1 = rowptr[node + 1];
  bool act = lane < 21;
  f32x4 a = {0.f, 0.f, 0.f, 0.f};
  if (act) a = bfq(*(const uint2*)&h1b[node * DIN + lane * 4]);
  int e = r0;
  for (; e + 4 <= r1; e += 4) {
    int s0 = csr[e], s1 = csr[e + 1], s2 = csr[e + 2], s3 = csr[e + 3];
    if (act) {
      uint2 q0 = *(const uint2*)&h1b[s0 * DIN + lane * 4];
      uint2 q1 = *(const uint2*)&h1b[s1 * DIN + lane * 4];
      uint2 q2 = *(const uint2*)&h1b[s2 * DIN + lane * 4];
      uint2 q3 = *(const uint2*)&h1b[s3 * DIN + lane * 4];
      a += (bfq(q0) + bfq(q1)) + (bfq(q2) + bfq(q3));
    }
  }
  for (; e < r1; e++) {
    int s = csr[e];
    if (act) a += bfq(*(const uint2*)&h1b[s * DIN + lane * 4]);
  }
  if (lane < 24) {
    uint2 p;
    if (act) {
      p.x = (unsigned int)f2bf(a.x) | ((unsigned int)f2bf(a.y) << 16);
      p.y = (unsigned int)f2bf(a.z) | ((unsigned int)f2bf(a.w) << 16);
    } else {
      p.x = 0u; p.y = 0u;   // zero K-pad cols 84..95
    }
    *(uint2*)&out[node * 96 + lane * 4] = p;
  }
}

// ---------------- W1^T split hi/lo bf16, padded [96][96] ----------------
__global__ __launch_bounds__(256) void k_w1t(const float* __restrict__ W1, unsigned short* __restrict__ w1h,
                                             unsigned short* __restrict__ w1l) {
  int idx = blockIdx.x * 256 + threadIdx.x;
  if (idx >= 96 * 96) return;
  int n = idx / 96, k = idx % 96;
  float v = (n < DIN && k < DIN) ? W1[k * DIN + n] : 0.f;
  unsigned short h = f2bf(v);
  w1h[idx] = h;
  w1l[idx] = f2bf(v - bf2f(h));
}

// ---------------- conv1 via MFMA, split-bf16; h1 emitted as bf16 ----------------
__global__ __launch_bounds__(256) void k_conv1m(const float* __restrict__ agg,
                                                const unsigned short* __restrict__ w1h,
                                                const unsigned short* __restrict__ w1l,
                                                const float* __restrict__ b1,
                                                unsigned short* __restrict__ h1b) {
  constexpr int LDA = 104;
  __shared__ __align__(16) unsigned short Ah[64 * LDA];
  __shared__ __align__(16) unsigned short Al[64 * LDA];
  int t = threadIdx.x;
  int m0 = blockIdx.x * 64;

  for (int idx = t; idx < 64 * 21; idx += 256) {
    int r = idx / 21, c = idx - r * 21;
    int row = m0 + r;
    f32x4 v = {0.f, 0.f, 0.f, 0.f};
    if (row < N_NODES) v = *(const f32x4*)&agg[row * DIN + c * 4];
    unsigned short h0 = f2bf(v.x), h1_ = f2bf(v.y), h2_ = f2bf(v.z), h3_ = f2bf(v.w);
    unsigned short l0 = f2bf(v.x - bf2f(h0)), l1 = f2bf(v.y - bf2f(h1_));
    unsigned short l2 = f2bf(v.z - bf2f(h2_)), l3 = f2bf(v.w - bf2f(h3_));
    unsigned int* ph = (unsigned int*)&Ah[r * LDA + c * 4];
    ph[0] = (unsigned int)h0 | ((unsigned int)h1_ << 16);
    ph[1] = (unsigned int)h2_ | ((unsigned int)h3_ << 16);
    unsigned int* pl = (unsigned int*)&Al[r * LDA + c * 4];
    pl[0] = (unsigned int)l0 | ((unsigned int)l1 << 16);
    pl[1] = (unsigned int)l2 | ((unsigned int)l3 << 16);
  }
  for (int idx = t; idx < 64 * 6; idx += 256) {
    int r = idx / 6, c = idx - r * 6;
    ((unsigned int*)&Ah[r * LDA + 84])[c] = 0;
    ((unsigned int*)&Al[r * LDA + 84])[c] = 0;
  }
  __syncthreads();

  int w = t >> 6, l = t & 63;
  int lr = l & 15, lk = (l >> 4) * 8;
  bf16x8 ah[3], al[3];
  #pragma unroll
  for (int kk = 0; kk < 3; kk++) {
    ah[kk] = *(bf16x8*)&Ah[(w * 16 + lr) * LDA + lk + kk * 32];
    al[kk] = *(bf16x8*)&Al[(w * 16 + lr) * LDA + lk + kk * 32];
  }

  #pragma unroll
  for (int nt = 0; nt < 6; nt++) {
    f32x4 acc = {0.f, 0.f, 0.f, 0.f};
    #pragma unroll
    for (int kk = 0; kk < 3; kk++) {
      bf16x8 bh = *(const bf16x8*)&w1h[(nt * 16 + lr) * 96 + lk + kk * 32];
      bf16x8 bl = *(const bf16x8*)&w1l[(nt * 16 + lr) * 96 + lk + kk * 32];
      acc = __builtin_amdgcn_mfma_f32_16x16x32_bf16(ah[kk], bh, acc, 0, 0, 0);
      acc = __builtin_amdgcn_mfma_f32_16x16x32_bf16(al[kk], bh, acc, 0, 0, 0);
      acc = __builtin_amdgcn_mfma_f32_16x16x32_bf16(ah[kk], bl, acc, 0, 0, 0);
    }
    int col = nt * 16 + lr;
    if (col < DIN) {
      float bias = b1[col];
      int rbase = m0 + w * 16 + (l >> 4) * 4;
      #pragma unroll
      for (int j = 0; j < 4; j++) {
        if (rbase + j < N_NODES)
          h1b[(rbase + j) * DIN + col] = f2bf(fmaxf(acc[j] + bias, 0.f));
      }
    }
  }
}

// ---------------- W2^T in bf16, padded [896][96] ----------------
__global__ __launch_bounds__(256) void k_w2t(const float* __restrict__ W2, unsigned short* __restrict__ w2t) {
  int idx = blockIdx.x * 256 + threadIdx.x;
  if (idx >= 896 * 96) return;
  int n = idx / 96, k = idx % 96;
  float v = (n < DHID && k < DIN) ? W2[k * DHID + n] : 0.f;
  w2t[idx] = f2bf(v);
}

// ---------------- conv2 + pooling stage 1: 128-row blocks, uniform fast path ----------
// 4 waves: wave w owns rows m0+(w&1)*64.. and nc chunks {nc % 2 == w>>1}. LDS atomics
// combine; per-block partials flushed with plain stores. Fast path (uniform, in-range
// block, ~84%) skips graph-membership compares and the seg1 arrays entirely.
__global__ __launch_bounds__(256) void k_conv2pool3(const unsigned short* __restrict__ aggb,
                                                    const unsigned short* __restrict__ w2t,
                                                    const float* __restrict__ b2,
                                                    const int* __restrict__ batch,
                                                    int* __restrict__ pm0, float* __restrict__ ps0,
                                                    int* __restrict__ pm1, float* __restrict__ ps1,
                                                    int* __restrict__ blkg,
                                                    int* __restrict__ maxb, float* __restrict__ sump) {
  __shared__ int   smax0[DHID]; __shared__ float ssum0[DHID];
  __shared__ int   smax1[DHID]; __shared__ float ssum1[DHID];
  int t = threadIdx.x;
  int w = t >> 6, l = t & 63;
  int b = blockIdx.x;
  int m0 = b * 128;
  int r0 = m0 + (w & 1) * 64;
  int lr = l & 15, hi = l >> 4, lk = hi * 8;

  for (int i = t; i < DHID; i += 256) { smax0[i] = 0; ssum0[i] = 0.f; smax1[i] = 0; ssum1[i] = 0.f; }

  // A fragments: 4 row-groups x 3 k-chunks
  bf16x8 afr[4][3];
  #pragma unroll
  for (int rg = 0; rg < 4; rg++) {
    int row = r0 + rg * 16 + lr;
    #pragma unroll
    for (int kk = 0; kk < 3; kk++) {
      bf16x8 v = {0, 0, 0, 0, 0, 0, 0, 0};
      if (row < N_NODES) v = *(const bf16x8*)&aggb[row * 96 + lk + kk * 32];
      afr[rg][kk] = v;
    }
  }

  int g0 = batch[m0];
  int g1 = batch[min(m0 + 127, N_NODES - 1)];
  bool fast = (g0 == g1) && (m0 + 127 < N_NODES);
  __syncthreads();

  if (fast) {
    for (int nc = (w >> 1); nc < 14; nc += 2) {
      #pragma unroll
      for (int nt = 0; nt < 4; nt++) {
        int c = nc * 64 + nt * 16 + lr;
        const unsigned short* bp = &w2t[(nc * 64 + nt * 16 + lr) * 96 + lk];
        bf16x8 b0v = *(const bf16x8*)(bp);
        bf16x8 b1v = *(const bf16x8*)(bp + 32);
        bf16x8 b2v = *(const bf16x8*)(bp + 64);
        float bias = (c < DHID) ? b2[c] : 0.f;
        float mx = 0.f, sm = 0.f;
        #pragma unroll
        for (int rg = 0; rg < 4; rg++) {
          f32x4 a_ = {0.f, 0.f, 0.f, 0.f};
          a_ = __builtin_amdgcn_mfma_f32_16x16x32_bf16(afr[rg][0], b0v, a_, 0, 0, 0);
          a_ = __builtin_amdgcn_mfma_f32_16x16x32_bf16(afr[rg][1], b1v, a_, 0, 0, 0);
          a_ = __builtin_amdgcn_mfma_f32_16x16x32_bf16(afr[rg][2], b2v, a_, 0, 0, 0);
          #pragma unroll
          for (int j = 0; j < 4; j++) {
            float v = fmaxf(a_[j] + bias, 0.f);
            mx = fmaxf(mx, v); sm += v;
          }
        }
        mx = fmaxf(mx, __shfl_xor(mx, 16)); sm += __shfl_xor(sm, 16);
        mx = fmaxf(mx, __shfl_xor(mx, 32)); sm += __shfl_xor(sm, 32);
        if (hi == 0 && c < DHID) {
          atomicMax(&smax0[c], __float_as_int(mx));
          atomicAdd(&ssum0[c], sm);
        }
      }
    }
  } else {
    int grow[4][4];
    #pragma unroll
    for (int rg = 0; rg < 4; rg++)
      #pragma unroll
      for (int j = 0; j < 4; j++) {
        int row = r0 + rg * 16 + hi * 4 + j;
        grow[rg][j] = (row < N_NODES) ? batch[row] : -1;
      }
    for (int nc = (w >> 1); nc < 14; nc += 2) {
      #pragma unroll
      for (int nt = 0; nt < 4; nt++) {
        int c = nc * 64 + nt * 16 + lr;
        const unsigned short* bp = &w2t[(nc * 64 + nt * 16 + lr) * 96 + lk];
        bf16x8 b0v = *(const bf16x8*)(bp);
        bf16x8 b1v = *(const bf16x8*)(bp + 32);
        bf16x8 b2v = *(const bf16x8*)(bp + 64);
        float bias = (c < DHID) ? b2[c] : 0.f;
        float mx0 = 0.f, sm0 = 0.f, mx1 = 0.f, sm1 = 0.f;
        float vv[4][4];
        #pragma unroll
        for (int rg = 0; rg < 4; rg++) {
          f32x4 a_ = {0.f, 0.f, 0.f, 0.f};
          a_ = __builtin_amdgcn_mfma_f32_16x16x32_bf16(afr[rg][0], b0v, a_, 0, 0, 0);
          a_ = __builtin_amdgcn_mfma_f32_16x16x32_bf16(afr[rg][1], b1v, a_, 0, 0, 0);
          a_ = __builtin_amdgcn_mfma_f32_16x16x32_bf16(afr[rg][2], b2v, a_, 0, 0, 0);
          #pragma unroll
          for (int j = 0; j < 4; j++) {
            float v = fmaxf(a_[j] + bias, 0.f);
            vv[rg][j] = v;
            if (grow[rg][j] == g0) { mx0 = fmaxf(mx0, v); sm0 += v; }
            if (grow[rg][j] == g1) { mx1 = fmaxf(mx1, v); sm1 += v; }
          }
        }
        mx0 = fmaxf(mx0, __shfl_xor(mx0, 16)); sm0 += __shfl_xor(sm0, 16);
        mx0 = fmaxf(mx0, __shfl_xor(mx0, 32)); sm0 += __shfl_xor(sm0, 32);
        mx1 = fmaxf(mx1, __shfl_xor(mx1, 16)); sm1 += __shfl_xor(sm1, 16);
        mx1 = fmaxf(mx1, __shfl_xor(mx1, 32)); sm1 += __shfl_xor(sm1, 32);
        if (hi == 0 && c < DHID) {
          atomicMax(&smax0[c], __float_as_int(mx0));
          atomicAdd(&ssum0[c], sm0);
          atomicMax(&smax1[c], __float_as_int(mx1));
          atomicAdd(&ssum1[c], sm1);
        }
        if (g1 - g0 >= 2) {  // pathological middle segments
          for (int g = g0 + 1; g < g1; g++) {
            float mx = 0.f, sm = 0.f;
            #pragma unroll
            for (int rg = 0; rg < 4; rg++)
              #pragma unroll
              for (int j = 0; j < 4; j++)
                if (grow[rg][j] == g) { mx = fmaxf(mx, vv[rg][j]); sm += vv[rg][j]; }
            mx = fmaxf(mx, __shfl_xor(mx, 16)); sm += __shfl_xor(sm, 16);
            mx = fmaxf(mx, __shfl_xor(mx, 32)); sm += __shfl_xor(sm, 32);
            if (hi == 0 && c < DHID) {
              atomicMax(&maxb[g * DHID + c], __float_as_int(mx));
              atomicAdd(&sump[g * DHID + c], sm);
            }
          }
        }
      }
    }
  }
  __syncthreads();
  for (int i = t; i < DHID; i += 256) {
    pm0[b * DHID + i] = smax0[i];
    ps0[b * DHID + i] = ssum0[i];
  }
  if (g0 != g1) {
    for (int i = t; i < DHID; i += 256) {
      pm1[b * DHID + i] = smax1[i];
      ps1[b * DHID + i] = ssum1[i];
    }
  }
  if (t == 0) { blkg[b * 2] = g0; blkg[b * 2 + 1] = g1; }
}

// ---------------- pooling stage 2: merge partials, write z = [maxp | meanp] --------------
__global__ __launch_bounds__(256) void k_pool2(const int* __restrict__ pm0, const float* __restrict__ ps0,
                                               const int* __restrict__ pm1, const float* __restrict__ ps1,
                                               const int* __restrict__ blkg, const int* __restrict__ cnt,
                                               const int* __restrict__ maxb, const float* __restrict__ sump,
                                               float* __restrict__ z) {
  __shared__ int sstart[NGRAPH];
  int g = blockIdx.x, t = threadIdx.x;
  if (t == 0) {
    int s = 0;
    for (int i = 0; i < NGRAPH; i++) { sstart[i] = s; s += cnt[i]; }
  }
  __syncthreads();
  int c0 = cnt[g];
  int ns = sstart[g], ne = ns + c0;
  int b0 = ns / 128, b1 = (c0 > 0) ? (ne - 1) / 128 : b0 - 1;
  for (int c = t; c < DHID; c += 256) {
    float mx = __int_as_float(maxb[g * DHID + c]);  // >= 0; fallback buffer
    float sm = sump[g * DHID + c];
    for (int b = b0; b <= b1; b++) {
      int gg0 = blkg[2 * b], gg1 = blkg[2 * b + 1];
      if (gg0 == g)      { mx = fmaxf(mx, __int_as_float(pm0[b * DHID + c])); sm += ps0[b * DHID + c]; }
      else if (gg1 == g) { mx = fmaxf(mx, __int_as_float(pm1[b * DHID + c])); sm += ps1[b * DHID + c]; }
    }
    z[g * (2 * DHID) + c] = (c0 > 0) ? mx : 0.f;
    z[g * (2 * DHID) + DHID + c] = sm / (float)max(c0, 1);
  }
}

// ---------------- MLP partial GEMM (f32, k-split, atomic accumulate) ----------------
template <int KTOT, int NTOT, int KC>
__global__ __launch_bounds__(256) void k_mlp(const float* __restrict__ Zin, const float* __restrict__ W,
                                             float* __restrict__ accout) {
  __shared__ float zt[128 * KC];
  int t = threadIdx.x;
  constexpr int NCH = NTOT / 64;
  int nc = blockIdx.x % NCH, kc = blockIdx.x / NCH;
  int k0 = kc * KC, n0 = nc * 64;
  for (int idx = t; idx < 128 * (KC / 4); idx += 256) {
    int r = idx / (KC / 4), c = idx % (KC / 4);
    *(f32x4*)&zt[r * KC + c * 4] = *(const f32x4*)&Zin[r * KTOT + k0 + c * 4];
  }
  __syncthreads();
  int nl = (t & 15) * 4, mg = t >> 4;
  f32x4 acc[8];
  #pragma unroll
  for (int mm = 0; mm < 8; mm++) acc[mm] = (f32x4){0.f, 0.f, 0.f, 0.f};
  #pragma unroll 4
  for (int k = 0; k < KC; k++) {
    f32x4 w4 = *(const f32x4*)&W[(k0 + k) * NTOT + n0 + nl];
    #pragma unroll
    for (int mm = 0; mm < 8; mm++) acc[mm] += zt[(mg * 8 + mm) * KC + k] * w4;
  }
  #pragma unroll
  for (int mm = 0; mm < 8; mm++)
    #pragma unroll
    for (int j = 0; j < 4; j++)
      atomicAdd(&accout[(mg * 8 + mm) * NTOT + n0 + nl + j], acc[mm][j]);
}

__global__ __launch_bounds__(256) void k_bias_relu(float* __restrict__ X, const float* __restrict__ b,
                                                   int NTOT, int total, int relu) {
  int i = blockIdx.x * 256 + threadIdx.x;
  if (i >= total) return;
  float v = X[i] + b[i % NTOT];
  X[i] = relu ? fmaxf(v, 0.f) : v;
}

// ---------------- launch ----------------
static constexpr size_t AL(size_t x) { return (x + 255) & ~(size_t)255; }

extern "C" void kernel_launch(void* const* d_in, const int* in_sizes, int n_in,
                              void* d_out, int out_size, void* d_ws, size_t ws_size,
                              hipStream_t stream) {
  const float* x   = (const float*)d_in[0];
  const int*  edge = (const int*)d_in[1];
  const int*  batch= (const int*)d_in[2];
  const float* W1  = (const float*)d_in[3];
  const float* b1  = (const float*)d_in[4];
  const float* W2  = (const float*)d_in[5];
  const float* b2  = (const float*)d_in[6];
  const float* Wg1 = (const float*)d_in[7];
  const float* bg1 = (const float*)d_in[8];
  const float* Wg2 = (const float*)d_in[9];
  const float* bg2 = (const float*)d_in[10];
  float* out = (float*)d_out;
  const int* src = edge;
  const int* dst = edge + N_EDGESC;

  size_t o = 0;
  size_t OFF_AGG = o;  o += AL((size_t)N_NODES * DIN * 4);   // reused for pooling partials
  size_t OFF_H1  = o;  o += AL((size_t)N_NODES * DIN * 4);
  size_t OFF_AGB = o;  o += AL((size_t)N_NODES * 96 * 2);
  size_t OFF_CSR = o;  o += AL((size_t)N_EDGESC * 4);
  size_t OFF_W2T = o;  o += AL((size_t)896 * 96 * 2);
  size_t OFF_W1H = o;  o += AL((size_t)96 * 96 * 2);
  size_t OFF_W1L = o;  o += AL((size_t)96 * 96 * 2);
  size_t OFF_RP  = o;  o += AL((size_t)(N_NODES + 1) * 4);
  size_t OFF_CUR = o;  o += AL((size_t)N_NODES * 4);
  size_t OFF_BS  = o;  o += AL(128 * 4);
  size_t OFF_BO  = o;  o += AL(128 * 4);
  size_t OFF_Z   = o;  o += AL((size_t)NGRAPH * 2 * DHID * 4);
  size_t OFF_DEG = o;  o += AL((size_t)N_NODES * 4);
  size_t OFF_MAX = o;  o += AL((size_t)NGRAPH * DHID * 4);
  size_t OFF_SUM = o;  o += AL((size_t)NGRAPH * DHID * 4);
  size_t OFF_CNT = o;  o += AL(NGRAPH * 4);
  size_t OFF_Z1  = o;  o += AL((size_t)NGRAPH * DF1 * 4);
  size_t TOTAL = o;
  size_t ZERO0 = OFF_DEG, ZEROB = TOTAL - OFF_DEG;
  if (ws_size < TOTAL) return;

  // pooling partials alias the agg region (agg's last reader, k_conv1m, runs before stage 1)
  size_t PB = AL((size_t)PBLK2 * DHID * 4);
  size_t OFF_PM0 = OFF_AGG;
  size_t OFF_PS0 = OFF_AGG + PB;
  size_t OFF_PM1 = OFF_AGG + 2 * PB;
  size_t OFF_PS1 = OFF_AGG + 3 * PB;
  size_t OFF_BLG = OFF_AGG + 4 * PB;   // 4*2.63MB + 6KB << 33.6MB

  char* ws = (char*)d_ws;
  float* agg = (float*)(ws + OFF_AGG);
  unsigned short* h1b = (unsigned short*)(ws + OFF_H1);
  unsigned short* aggb = (unsigned short*)(ws + OFF_AGB);
  int* csr   = (int*)(ws + OFF_CSR);
  unsigned short* w2t = (unsigned short*)(ws + OFF_W2T);
  unsigned short* w1h = (unsigned short*)(ws + OFF_W1H);
  unsigned short* w1l = (unsigned short*)(ws + OFF_W1L);
  int* rowptr = (int*)(ws + OFF_RP);
  int* cursor = (int*)(ws + OFF_CUR);
  int* bsum  = (int*)(ws + OFF_BS);
  int* boff  = (int*)(ws + OFF_BO);
  float* z   = (float*)(ws + OFF_Z);
  int* deg   = (int*)(ws + OFF_DEG);
  int* maxb  = (int*)(ws + OFF_MAX);
  float* sump= (float*)(ws + OFF_SUM);
  int* cnt   = (int*)(ws + OFF_CNT);
  float* z1  = (float*)(ws + OFF_Z1);
  int* pm0   = (int*)(ws + OFF_PM0);
  float* ps0 = (float*)(ws + OFF_PS0);
  int* pm1   = (int*)(ws + OFF_PM1);
  float* ps1 = (float*)(ws + OFF_PS1);
  int* blkg  = (int*)(ws + OFF_BLG);

  hipMemsetAsync(ws + ZERO0, 0, ZEROB, stream);
  hipMemsetAsync(d_out, 0, (size_t)out_size * 4, stream);

  k_w2t<<<(896 * 96 + 255) / 256, 256, 0, stream>>>(W2, w2t);
  k_w1t<<<(96 * 96 + 255) / 256, 256, 0, stream>>>(W1, w1h, w1l);
  k_deg<<<N_EDGESC / 256, 256, 0, stream>>>(dst, deg);
  k_scan1<<<SBLOCKS, 256, 0, stream>>>(deg, bsum);
  k_scan2<<<1, 128, 0, stream>>>(bsum, boff);
  k_scan3<<<SBLOCKS, 256, 0, stream>>>(deg, boff, rowptr, cursor);
  k_fill<<<N_EDGESC / 256, 256, 0, stream>>>(src, dst, cursor, csr);
  k_counts<<<(N_NODES + 2047) / 2048, 256, 0, stream>>>(batch, cnt);

  k_agg1<<<(N_NODES + 7) / 8, 256, 0, stream>>>(x, rowptr, csr, agg);
  k_conv1m<<<(N_NODES + 63) / 64, 256, 0, stream>>>(agg, w1h, w1l, b1, h1b);
  k_agg2<<<(N_NODES + 7) / 8, 256, 0, stream>>>(h1b, rowptr, csr, aggb);
  k_conv2pool3<<<PBLK2, 256, 0, stream>>>(aggb, w2t, b2, batch, pm0, ps0, pm1, ps1, blkg, maxb, sump);
  k_pool2<<<NGRAPH, 256, 0, stream>>>(pm0, ps0, pm1, ps1, blkg, cnt, maxb, sump, z);

  k_mlp<2 * DHID, DF1, 120><<<(DF1 / 64) * (2 * DHID / 120), 256, 0, stream>>>(z, Wg1, z1);
  k_bias_relu<<<(NGRAPH * DF1 + 255) / 256, 256, 0, stream>>>(z1, bg1, DF1, NGRAPH * DF1, 1);
  k_mlp<DF1, DOUTC, 64><<<(DOUTC / 64) * (DF1 / 64), 256, 0, stream>>>(z1, Wg2, out);
  k_bias_relu<<<(NGRAPH * DOUTC + 255) / 256, 256, 0, stream>>>(out, bg2, DOUTC, NGRAPH * DOUTC, 0);
}

// Round 6
// 336.331 us; speedup vs baseline: 1.7050x; 1.1102x over previous
//
#include <hip/hip_runtime.h>

#define N_NODES 100000
#define N_EDGESC 800000
#define NGRAPH 128
#define DIN 84
#define DHID 840
#define DF1 1024
#define DOUTC 384
#define PBLK2 782   // ceil(N_NODES/128)
#define KP1 1696    // 2*DHID padded to x32

typedef __attribute__((ext_vector_type(4))) float f32x4;
typedef __attribute__((ext_vector_type(8))) short bf16x8;

__device__ __forceinline__ unsigned short f2bf(float f) {
  union { float f; unsigned int u; } v; v.f = f;
  unsigned int r = v.u + 0x7FFFu + ((v.u >> 16) & 1u);
  return (unsigned short)(r >> 16);
}
__device__ __forceinline__ float bf2f(unsigned short h) {
  union { unsigned int u; float f; } v; v.u = ((unsigned int)h) << 16;
  return v.f;
}

// ---------------- CSR build ----------------
__global__ __launch_bounds__(256) void k_deg(const int* __restrict__ dst, int* __restrict__ deg) {
  int e = blockIdx.x * 256 + threadIdx.x;
  if (e >= N_EDGESC) return;
  atomicAdd(&deg[dst[e]], 1);
}

#define SCHUNK 1024
#define SBLOCKS 98   // ceil(100000/1024)

__global__ __launch_bounds__(256) void k_scan1(const int* __restrict__ deg, int* __restrict__ bsum) {
  __shared__ int sd[256];
  int b = blockIdx.x, t = threadIdx.x;
  int base = b * SCHUNK + t * 4;
  int s = 0;
  for (int j = 0; j < 4; j++) { int i = base + j; if (i < N_NODES) s += deg[i]; }
  sd[t] = s; __syncthreads();
  for (int off = 128; off > 0; off >>= 1) {
    if (t < off) sd[t] += sd[t + off];
    __syncthreads();
  }
  if (t == 0) bsum[b] = sd[0];
}

__global__ __launch_bounds__(128) void k_scan2(const int* __restrict__ bsum, int* __restrict__ boff) {
  __shared__ int sd[128];
  int t = threadIdx.x;
  int v = (t < SBLOCKS) ? bsum[t] : 0;
  sd[t] = v; __syncthreads();
  for (int off = 1; off < 128; off <<= 1) {
    int add = (t >= off) ? sd[t - off] : 0;
    __syncthreads();
    sd[t] += add;
    __syncthreads();
  }
  if (t < SBLOCKS) boff[t] = sd[t] - v;
}

__global__ __launch_bounds__(256) void k_scan3(const int* __restrict__ deg, const int* __restrict__ boff,
                                               int* __restrict__ rowptr, int* __restrict__ cursor) {
  __shared__ int sd[256];
  int b = blockIdx.x, t = threadIdx.x;
  int base = b * SCHUNK + t * 4;
  int v[4]; int s = 0;
  for (int j = 0; j < 4; j++) { int i = base + j; v[j] = (i < N_NODES) ? deg[i] : 0; s += v[j]; }
  sd[t] = s; __syncthreads();
  for (int off = 1; off < 256; off <<= 1) {
    int add = (t >= off) ? sd[t - off] : 0;
    __syncthreads();
    sd[t] += add;
    __syncthreads();
  }
  int run = sd[t] - s + boff[b];
  for (int j = 0; j < 4; j++) {
    int i = base + j;
    if (i < N_NODES) { rowptr[i] = run; cursor[i] = run; }
    run += v[j];
  }
  if (b == 0 && t == 0) rowptr[N_NODES] = N_EDGESC;
}

__global__ __launch_bounds__(256) void k_fill(const int* __restrict__ src, const int* __restrict__ dst,
                                              int* __restrict__ cursor, int* __restrict__ csr) {
  int e = blockIdx.x * 256 + threadIdx.x;
  if (e >= N_EDGESC) return;
  int d = dst[e];
  int pos = atomicAdd(&cursor[d], 1);
  csr[pos] = src[e];
}

// ---------------- per-graph node counts ----------------
__global__ __launch_bounds__(256) void k_counts(const int* __restrict__ batch, int* __restrict__ cnt) {
  __shared__ int h[NGRAPH];
  int t = threadIdx.x;
  if (t < NGRAPH) h[t] = 0;
  __syncthreads();
  int base = blockIdx.x * 2048;
  for (int j = 0; j < 8; j++) {
    int i = base + j * 256 + t;
    if (i < N_NODES) atomicAdd(&h[batch[i]], 1);
  }
  __syncthreads();
  if (t < NGRAPH && h[t] > 0) atomicAdd(&cnt[t], h[t]);
}

// ---------------- x -> bf16 copy (halves agg1's gather bytes) ----------------
__global__ __launch_bounds__(256) void k_xbf(const float* __restrict__ x, unsigned short* __restrict__ xb) {
  int i = (blockIdx.x * 256 + threadIdx.x) * 8;
  if (i >= N_NODES * DIN) return;
  f32x4 v0 = *(const f32x4*)&x[i];
  f32x4 v1 = *(const f32x4*)&x[i + 4];
  uint4 p;
  p.x = (unsigned int)f2bf(v0.x) | ((unsigned int)f2bf(v0.y) << 16);
  p.y = (unsigned int)f2bf(v0.z) | ((unsigned int)f2bf(v0.w) << 16);
  p.z = (unsigned int)f2bf(v1.x) | ((unsigned int)f2bf(v1.y) << 16);
  p.w = (unsigned int)f2bf(v1.z) | ((unsigned int)f2bf(v1.w) << 16);
  *(uint4*)&xb[i] = p;
}

__device__ __forceinline__ f32x4 bfq(uint2 p) {
  f32x4 r;
  r.x = bf2f((unsigned short)(p.x & 0xffff)); r.y = bf2f((unsigned short)(p.x >> 16));
  r.z = bf2f((unsigned short)(p.y & 0xffff)); r.w = bf2f((unsigned short)(p.y >> 16));
  return r;
}

// ---------------- agg1: bf16 gather (stride 84), f32 out (stride 84) ----------------
__global__ __launch_bounds__(256) void k_agg1b(const unsigned short* __restrict__ xb, const int* __restrict__ rowptr,
                                               const int* __restrict__ csr, float* __restrict__ out) {
  int node = blockIdx.x * 8 + (threadIdx.x >> 5);
  int lane = threadIdx.x & 31;
  if (node >= N_NODES) return;
  int r0 = rowptr[node], r1 = rowptr[node + 1];
  bool act = lane < 21;
  f32x4 a = {0.f, 0.f, 0.f, 0.f};
  if (act) a = bfq(*(const uint2*)&xb[node * DIN + lane * 4]);
  int e = r0;
  for (; e + 4 <= r1; e += 4) {
    int s0 = csr[e], s1 = csr[e + 1], s2 = csr[e + 2], s3 = csr[e + 3];
    if (act) {
      uint2 q0 = *(const uint2*)&xb[s0 * DIN + lane * 4];
      uint2 q1 = *(const uint2*)&xb[s1 * DIN + lane * 4];
      uint2 q2 = *(const uint2*)&xb[s2 * DIN + lane * 4];
      uint2 q3 = *(const uint2*)&xb[s3 * DIN + lane * 4];
      a += (bfq(q0) + bfq(q1)) + (bfq(q2) + bfq(q3));
    }
  }
  for (; e < r1; e++) {
    int s = csr[e];
    if (act) a += bfq(*(const uint2*)&xb[s * DIN + lane * 4]);
  }
  if (act) ((f32x4*)out)[node * 21 + lane] = a;
}

// ---------------- agg2: bf16 in (stride 84), bf16 out (stride 96, zero-pad) ----------------
__global__ __launch_bounds__(256) void k_agg2(const unsigned short* __restrict__ h1b, const int* __restrict__ rowptr,
                                              const int* __restrict__ csr, unsigned short* __restrict__ out) {
  int node = blockIdx.x * 8 + (threadIdx.x >> 5);
  int lane = threadIdx.x & 31;
  if (node >= N_NODES) return;
  int r0 = rowptr[node], r1 = rowptr[node + 1];
  bool act = lane < 21;
  f32x4 a = {0.f, 0.f, 0.f, 0.f};
  if (act) a = bfq(*(const uint2*)&h1b[node * DIN + lane * 4]);
  int e = r0;
  for (; e + 4 <= r1; e += 4) {
    int s0 = csr[e], s1 = csr[e + 1], s2 = csr[e + 2], s3 = csr[e + 3];
    if (act) {
      uint2 q0 = *(const uint2*)&h1b[s0 * DIN + lane * 4];
      uint2 q1 = *(const uint2*)&h1b[s1 * DIN + lane * 4];
      uint2 q2 = *(const uint2*)&h1b[s2 * DIN + lane * 4];
      uint2 q3 = *(const uint2*)&h1b[s3 * DIN + lane * 4];
      a += (bfq(q0) + bfq(q1)) + (bfq(q2) + bfq(q3));
    }
  }
  for (; e < r1; e++) {
    int s = csr[e];
    if (act) a += bfq(*(const uint2*)&h1b[s * DIN + lane * 4]);
  }
  if (lane < 24) {
    uint2 p;
    if (act) {
      p.x = (unsigned int)f2bf(a.x) | ((unsigned int)f2bf(a.y) << 16);
      p.y = (unsigned int)f2bf(a.z) | ((unsigned int)f2bf(a.w) << 16);
    } else {
      p.x = 0u; p.y = 0u;   // zero K-pad cols 84..95
    }
    *(uint2*)&out[node * 96 + lane * 4] = p;
  }
}

// ---------------- W1^T split hi/lo bf16, padded [96][96] ----------------
__global__ __launch_bounds__(256) void k_w1t(const float* __restrict__ W1, unsigned short* __restrict__ w1h,
                                             unsigned short* __restrict__ w1l) {
  int idx = blockIdx.x * 256 + threadIdx.x;
  if (idx >= 96 * 96) return;
  int n = idx / 96, k = idx % 96;
  float v = (n < DIN && k < DIN) ? W1[k * DIN + n] : 0.f;
  unsigned short h = f2bf(v);
  w1h[idx] = h;
  w1l[idx] = f2bf(v - bf2f(h));
}

// ---------------- generic W [K][N] -> transposed hi/lo bf16 [N][KP] ----------------
template <int K, int KPAD, int N>
__global__ __launch_bounds__(256) void k_wsplit(const float* __restrict__ W,
                                                unsigned short* __restrict__ wh,
                                                unsigned short* __restrict__ wl) {
  __shared__ float tile[32][33];
  int b = blockIdx.x;
  int kt = b % (KPAD / 32), nt = b / (KPAD / 32);
  int k0 = kt * 32, n0 = nt * 32;
  int t = threadIdx.x;
  int r = t >> 3, c4 = (t & 7) * 4;
  int k = k0 + r;
  f32x4 v = {0.f, 0.f, 0.f, 0.f};
  if (k < K) v = *(const f32x4*)&W[(size_t)k * N + n0 + c4];
  tile[r][c4 + 0] = v.x; tile[r][c4 + 1] = v.y; tile[r][c4 + 2] = v.z; tile[r][c4 + 3] = v.w;
  __syncthreads();
  int n = t >> 3;
  float f0 = tile[c4 + 0][n], f1 = tile[c4 + 1][n], f2 = tile[c4 + 2][n], f3 = tile[c4 + 3][n];
  unsigned short h0 = f2bf(f0), h1_ = f2bf(f1), h2_ = f2bf(f2), h3_ = f2bf(f3);
  uint2 ph, pl;
  ph.x = (unsigned int)h0 | ((unsigned int)h1_ << 16);
  ph.y = (unsigned int)h2_ | ((unsigned int)h3_ << 16);
  pl.x = (unsigned int)f2bf(f0 - bf2f(h0)) | ((unsigned int)f2bf(f1 - bf2f(h1_)) << 16);
  pl.y = (unsigned int)f2bf(f2 - bf2f(h2_)) | ((unsigned int)f2bf(f3 - bf2f(h3_)) << 16);
  *(uint2*)&wh[(size_t)(n0 + n) * KPAD + k0 + c4] = ph;
  *(uint2*)&wl[(size_t)(n0 + n) * KPAD + k0 + c4] = pl;
}

// ---------------- conv1 via MFMA, split-bf16; h1 emitted as bf16 ----------------
__global__ __launch_bounds__(256) void k_conv1m(const float* __restrict__ agg,
                                                const unsigned short* __restrict__ w1h,
                                                const unsigned short* __restrict__ w1l,
                                                const float* __restrict__ b1,
                                                unsigned short* __restrict__ h1b) {
  constexpr int LDA = 104;
  __shared__ __align__(16) unsigned short Ah[64 * LDA];
  __shared__ __align__(16) unsigned short Al[64 * LDA];
  int t = threadIdx.x;
  int m0 = blockIdx.x * 64;

  for (int idx = t; idx < 64 * 21; idx += 256) {
    int r = idx / 21, c = idx - r * 21;
    int row = m0 + r;
    f32x4 v = {0.f, 0.f, 0.f, 0.f};
    if (row < N_NODES) v = *(const f32x4*)&agg[row * DIN + c * 4];
    unsigned short h0 = f2bf(v.x), h1_ = f2bf(v.y), h2_ = f2bf(v.z), h3_ = f2bf(v.w);
    unsigned short l0 = f2bf(v.x - bf2f(h0)), l1 = f2bf(v.y - bf2f(h1_));
    unsigned short l2 = f2bf(v.z - bf2f(h2_)), l3 = f2bf(v.w - bf2f(h3_));
    unsigned int* ph = (unsigned int*)&Ah[r * LDA + c * 4];
    ph[0] = (unsigned int)h0 | ((unsigned int)h1_ << 16);
    ph[1] = (unsigned int)h2_ | ((unsigned int)h3_ << 16);
    unsigned int* pl = (unsigned int*)&Al[r * LDA + c * 4];
    pl[0] = (unsigned int)l0 | ((unsigned int)l1 << 16);
    pl[1] = (unsigned int)l2 | ((unsigned int)l3 << 16);
  }
  for (int idx = t; idx < 64 * 6; idx += 256) {
    int r = idx / 6, c = idx - r * 6;
    ((unsigned int*)&Ah[r * LDA + 84])[c] = 0;
    ((unsigned int*)&Al[r * LDA + 84])[c] = 0;
  }
  __syncthreads();

  int w = t >> 6, l = t & 63;
  int lr = l & 15, lk = (l >> 4) * 8;
  bf16x8 ah[3], al[3];
  #pragma unroll
  for (int kk = 0; kk < 3; kk++) {
    ah[kk] = *(bf16x8*)&Ah[(w * 16 + lr) * LDA + lk + kk * 32];
    al[kk] = *(bf16x8*)&Al[(w * 16 + lr) * LDA + lk + kk * 32];
  }

  #pragma unroll
  for (int nt = 0; nt < 6; nt++) {
    f32x4 acc = {0.f, 0.f, 0.f, 0.f};
    #pragma unroll
    for (int kk = 0; kk < 3; kk++) {
      bf16x8 bh = *(const bf16x8*)&w1h[(nt * 16 + lr) * 96 + lk + kk * 32];
      bf16x8 bl = *(const bf16x8*)&w1l[(nt * 16 + lr) * 96 + lk + kk * 32];
      acc = __builtin_amdgcn_mfma_f32_16x16x32_bf16(ah[kk], bh, acc, 0, 0, 0);
      acc = __builtin_amdgcn_mfma_f32_16x16x32_bf16(al[kk], bh, acc, 0, 0, 0);
      acc = __builtin_amdgcn_mfma_f32_16x16x32_bf16(ah[kk], bl, acc, 0, 0, 0);
    }
    int col = nt * 16 + lr;
    if (col < DIN) {
      float bias = b1[col];
      int rbase = m0 + w * 16 + (l >> 4) * 4;
      #pragma unroll
      for (int j = 0; j < 4; j++) {
        if (rbase + j < N_NODES)
          h1b[(rbase + j) * DIN + col] = f2bf(fmaxf(acc[j] + bias, 0.f));
      }
    }
  }
}

// ---------------- W2^T in bf16, padded [896][96] ----------------
__global__ __launch_bounds__(256) void k_w2t(const float* __restrict__ W2, unsigned short* __restrict__ w2t) {
  int idx = blockIdx.x * 256 + threadIdx.x;
  if (idx >= 896 * 96) return;
  int n = idx / 96, k = idx % 96;
  float v = (n < DHID && k < DIN) ? W2[k * DHID + n] : 0.f;
  w2t[idx] = f2bf(v);
}

// ---------------- conv2 + pooling stage 1: 128-row blocks, uniform fast path ----------
__global__ __launch_bounds__(256) void k_conv2pool3(const unsigned short* __restrict__ aggb,
                                                    const unsigned short* __restrict__ w2t,
                                                    const float* __restrict__ b2,
                                                    const int* __restrict__ batch,
                                                    int* __restrict__ pm0, float* __restrict__ ps0,
                                                    int* __restrict__ pm1, float* __restrict__ ps1,
                                                    int* __restrict__ blkg,
                                                    int* __restrict__ maxb, float* __restrict__ sump) {
  __shared__ int   smax0[DHID]; __shared__ float ssum0[DHID];
  __shared__ int   smax1[DHID]; __shared__ float ssum1[DHID];
  int t = threadIdx.x;
  int w = t >> 6, l = t & 63;
  int b = blockIdx.x;
  int m0 = b * 128;
  int r0 = m0 + (w & 1) * 64;
  int lr = l & 15, hi = l >> 4, lk = hi * 8;

  for (int i = t; i < DHID; i += 256) { smax0[i] = 0; ssum0[i] = 0.f; smax1[i] = 0; ssum1[i] = 0.f; }

  bf16x8 afr[4][3];
  #pragma unroll
  for (int rg = 0; rg < 4; rg++) {
    int row = r0 + rg * 16 + lr;
    #pragma unroll
    for (int kk = 0; kk < 3; kk++) {
      bf16x8 v = {0, 0, 0, 0, 0, 0, 0, 0};
      if (row < N_NODES) v = *(const bf16x8*)&aggb[row * 96 + lk + kk * 32];
      afr[rg][kk] = v;
    }
  }

  int g0 = batch[m0];
  int g1 = batch[min(m0 + 127, N_NODES - 1)];
  bool fast = (g0 == g1) && (m0 + 127 < N_NODES);
  __syncthreads();

  if (fast) {
    for (int nc = (w >> 1); nc < 14; nc += 2) {
      #pragma unroll
      for (int nt = 0; nt < 4; nt++) {
        int c = nc * 64 + nt * 16 + lr;
        const unsigned short* bp = &w2t[(nc * 64 + nt * 16 + lr) * 96 + lk];
        bf16x8 b0v = *(const bf16x8*)(bp);
        bf16x8 b1v = *(const bf16x8*)(bp + 32);
        bf16x8 b2v = *(const bf16x8*)(bp + 64);
        float bias = (c < DHID) ? b2[c] : 0.f;
        float mx = 0.f, sm = 0.f;
        #pragma unroll
        for (int rg = 0; rg < 4; rg++) {
          f32x4 a_ = {0.f, 0.f, 0.f, 0.f};
          a_ = __builtin_amdgcn_mfma_f32_16x16x32_bf16(afr[rg][0], b0v, a_, 0, 0, 0);
          a_ = __builtin_amdgcn_mfma_f32_16x16x32_bf16(afr[rg][1], b1v, a_, 0, 0, 0);
          a_ = __builtin_amdgcn_mfma_f32_16x16x32_bf16(afr[rg][2], b2v, a_, 0, 0, 0);
          #pragma unroll
          for (int j = 0; j < 4; j++) {
            float v = fmaxf(a_[j] + bias, 0.f);
            mx = fmaxf(mx, v); sm += v;
          }
        }
        mx = fmaxf(mx, __shfl_xor(mx, 16)); sm += __shfl_xor(sm, 16);
        mx = fmaxf(mx, __shfl_xor(mx, 32)); sm += __shfl_xor(sm, 32);
        if (hi == 0 && c < DHID) {
          atomicMax(&smax0[c], __float_as_int(mx));
          atomicAdd(&ssum0[c], sm);
        }
      }
    }
  } else {
    int grow[4][4];
    #pragma unroll
    for (int rg = 0; rg < 4; rg++)
      #pragma unroll
      for (int j = 0; j < 4; j++) {
        int row = r0 + rg * 16 + hi * 4 + j;
        grow[rg][j] = (row < N_NODES) ? batch[row] : -1;
      }
    for (int nc = (w >> 1); nc < 14; nc += 2) {
      #pragma unroll
      for (int nt = 0; nt < 4; nt++) {
        int c = nc * 64 + nt * 16 + lr;
        const unsigned short* bp = &w2t[(nc * 64 + nt * 16 + lr) * 96 + lk];
        bf16x8 b0v = *(const bf16x8*)(bp);
        bf16x8 b1v = *(const bf16x8*)(bp + 32);
        bf16x8 b2v = *(const bf16x8*)(bp + 64);
        float bias = (c < DHID) ? b2[c] : 0.f;
        float mx0 = 0.f, sm0 = 0.f, mx1 = 0.f, sm1 = 0.f;
        float vv[4][4];
        #pragma unroll
        for (int rg = 0; rg < 4; rg++) {
          f32x4 a_ = {0.f, 0.f, 0.f, 0.f};
          a_ = __builtin_amdgcn_mfma_f32_16x16x32_bf16(afr[rg][0], b0v, a_, 0, 0, 0);
          a_ = __builtin_amdgcn_mfma_f32_16x16x32_bf16(afr[rg][1], b1v, a_, 0, 0, 0);
          a_ = __builtin_amdgcn_mfma_f32_16x16x32_bf16(afr[rg][2], b2v, a_, 0, 0, 0);
          #pragma unroll
          for (int j = 0; j < 4; j++) {
            float v = fmaxf(a_[j] + bias, 0.f);
            vv[rg][j] = v;
            if (grow[rg][j] == g0) { mx0 = fmaxf(mx0, v); sm0 += v; }
            if (grow[rg][j] == g1) { mx1 = fmaxf(mx1, v); sm1 += v; }
          }
        }
        mx0 = fmaxf(mx0, __shfl_xor(mx0, 16)); sm0 += __shfl_xor(sm0, 16);
        mx0 = fmaxf(mx0, __shfl_xor(mx0, 32)); sm0 += __shfl_xor(sm0, 32);
        mx1 = fmaxf(mx1, __shfl_xor(mx1, 16)); sm1 += __shfl_xor(sm1, 16);
        mx1 = fmaxf(mx1, __shfl_xor(mx1, 32)); sm1 += __shfl_xor(sm1, 32);
        if (hi == 0 && c < DHID) {
          atomicMax(&smax0[c], __float_as_int(mx0));
          atomicAdd(&ssum0[c], sm0);
          atomicMax(&smax1[c], __float_as_int(mx1));
          atomicAdd(&ssum1[c], sm1);
        }
        if (g1 - g0 >= 2) {
          for (int g = g0 + 1; g < g1; g++) {
            float mx = 0.f, sm = 0.f;
            #pragma unroll
            for (int rg = 0; rg < 4; rg++)
              #pragma unroll
              for (int j = 0; j < 4; j++)
                if (grow[rg][j] == g) { mx = fmaxf(mx, vv[rg][j]); sm += vv[rg][j]; }
            mx = fmaxf(mx, __shfl_xor(mx, 16)); sm += __shfl_xor(sm, 16);
            mx = fmaxf(mx, __shfl_xor(mx, 32)); sm += __shfl_xor(sm, 32);
            if (hi == 0 && c < DHID) {
              atomicMax(&maxb[g * DHID + c], __float_as_int(mx));
              atomicAdd(&sump[g * DHID + c], sm);
            }
          }
        }
      }
    }
  }
  __syncthreads();
  for (int i = t; i < DHID; i += 256) {
    pm0[b * DHID + i] = smax0[i];
    ps0[b * DHID + i] = ssum0[i];
  }
  if (g0 != g1) {
    for (int i = t; i < DHID; i += 256) {
      pm1[b * DHID + i] = smax1[i];
      ps1[b * DHID + i] = ssum1[i];
    }
  }
  if (t == 0) { blkg[b * 2] = g0; blkg[b * 2 + 1] = g1; }
}

// ---------------- pooling stage 2: merge partials, emit z as hi/lo bf16 [128][KP1] --------
__global__ __launch_bounds__(256) void k_pool2(const int* __restrict__ pm0, const float* __restrict__ ps0,
                                               const int* __restrict__ pm1, const float* __restrict__ ps1,
                                               const int* __restrict__ blkg, const int* __restrict__ cnt,
                                               const int* __restrict__ maxb, const float* __restrict__ sump,
                                               unsigned short* __restrict__ zh, unsigned short* __restrict__ zl) {
  __shared__ int sstart[NGRAPH];
  int g = blockIdx.x, t = threadIdx.x;
  if (t == 0) {
    int s = 0;
    for (int i = 0; i < NGRAPH; i++) { sstart[i] = s; s += cnt[i]; }
  }
  __syncthreads();
  int c0 = cnt[g];
  int ns = sstart[g], ne = ns + c0;
  int b0 = ns / 128, b1 = (c0 > 0) ? (ne - 1) / 128 : b0 - 1;
  for (int c = t; c < DHID; c += 256) {
    float mx = __int_as_float(maxb[g * DHID + c]);
    float sm = sump[g * DHID + c];
    for (int b = b0; b <= b1; b++) {
      int gg0 = blkg[2 * b], gg1 = blkg[2 * b + 1];
      if (gg0 == g)      { mx = fmaxf(mx, __int_as_float(pm0[b * DHID + c])); sm += ps0[b * DHID + c]; }
      else if (gg1 == g) { mx = fmaxf(mx, __int_as_float(pm1[b * DHID + c])); sm += ps1[b * DHID + c]; }
    }
    float vmax = (c0 > 0) ? mx : 0.f;
    float vmean = sm / (float)max(c0, 1);
    unsigned short hm = f2bf(vmax);
    zh[g * KP1 + c] = hm;
    zl[g * KP1 + c] = f2bf(vmax - bf2f(hm));
    unsigned short he = f2bf(vmean);
    zh[g * KP1 + DHID + c] = he;
    zl[g * KP1 + DHID + c] = f2bf(vmean - bf2f(he));
  }
  if (t < KP1 - 2 * DHID) {  // zero K-pad 1680..1695
    zh[g * KP1 + 2 * DHID + t] = 0;
    zl[g * KP1 + 2 * DHID + t] = 0;
  }
}

// ---------------- MLP1: z1 = relu(z @ Wg1 + bg1), split-bf16 MFMA, hi/lo out ----------------
__global__ __launch_bounds__(256) void k_mlp1m(const unsigned short* __restrict__ zh, const unsigned short* __restrict__ zl,
                                               const unsigned short* __restrict__ wh, const unsigned short* __restrict__ wl,
                                               const float* __restrict__ bg,
                                               unsigned short* __restrict__ z1h, unsigned short* __restrict__ z1l) {
  int t = threadIdx.x, w = t >> 6, l = t & 63;
  int lr = l & 15, hi = l >> 4, lk = hi * 8;
  int b = blockIdx.x;
  int n0 = (b >> 1) * 16;
  int m0 = (b & 1) * 64 + w * 16;
  const unsigned short* za = &zh[(size_t)(m0 + lr) * KP1 + lk];
  const unsigned short* zb = &zl[(size_t)(m0 + lr) * KP1 + lk];
  const unsigned short* wa = &wh[(size_t)(n0 + lr) * KP1 + lk];
  const unsigned short* wb = &wl[(size_t)(n0 + lr) * KP1 + lk];
  f32x4 acc = {0.f, 0.f, 0.f, 0.f};
  for (int ks = 0; ks < KP1 / 32; ks++) {
    bf16x8 ah = *(const bf16x8*)(za + ks * 32);
    bf16x8 al = *(const bf16x8*)(zb + ks * 32);
    bf16x8 bh = *(const bf16x8*)(wa + ks * 32);
    bf16x8 bl = *(const bf16x8*)(wb + ks * 32);
    acc = __builtin_amdgcn_mfma_f32_16x16x32_bf16(ah, bh, acc, 0, 0, 0);
    acc = __builtin_amdgcn_mfma_f32_16x16x32_bf16(al, bh, acc, 0, 0, 0);
    acc = __builtin_amdgcn_mfma_f32_16x16x32_bf16(ah, bl, acc, 0, 0, 0);
  }
  int col = n0 + lr;
  float bias = bg[col];
  #pragma unroll
  for (int j = 0; j < 4; j++) {
    int row = m0 + hi * 4 + j;
    float v = fmaxf(acc[j] + bias, 0.f);
    unsigned short h = f2bf(v);
    z1h[row * DF1 + col] = h;
    z1l[row * DF1 + col] = f2bf(v - bf2f(h));
  }
}

// ---------------- MLP2: out = z1 @ Wg2 + bg2, split-bf16 MFMA, f32 out ----------------
__global__ __launch_bounds__(256) void k_mlp2m(const unsigned short* __restrict__ z1h, const unsigned short* __restrict__ z1l,
                                               const unsigned short* __restrict__ wh, const unsigned short* __restrict__ wl,
                                               const float* __restrict__ bg, float* __restrict__ out) {
  int t = threadIdx.x, w = t >> 6, l = t & 63;
  int lr = l & 15, hi = l >> 4, lk = hi * 8;
  int b = blockIdx.x;
  int n0 = (b >> 1) * 16;
  int m0 = (b & 1) * 64 + w * 16;
  const unsigned short* za = &z1h[(size_t)(m0 + lr) * DF1 + lk];
  const unsigned short* zb = &z1l[(size_t)(m0 + lr) * DF1 + lk];
  const unsigned short* wa = &wh[(size_t)(n0 + lr) * DF1 + lk];
  const unsigned short* wb = &wl[(size_t)(n0 + lr) * DF1 + lk];
  f32x4 acc = {0.f, 0.f, 0.f, 0.f};
  for (int ks = 0; ks < DF1 / 32; ks++) {
    bf16x8 ah = *(const bf16x8*)(za + ks * 32);
    bf16x8 al = *(const bf16x8*)(zb + ks * 32);
    bf16x8 bh = *(const bf16x8*)(wa + ks * 32);
    bf16x8 bl = *(const bf16x8*)(wb + ks * 32);
    acc = __builtin_amdgcn_mfma_f32_16x16x32_bf16(ah, bh, acc, 0, 0, 0);
    acc = __builtin_amdgcn_mfma_f32_16x16x32_bf16(al, bh, acc, 0, 0, 0);
    acc = __builtin_amdgcn_mfma_f32_16x16x32_bf16(ah, bl, acc, 0, 0, 0);
  }
  int col = n0 + lr;
  float bias = bg[col];
  #pragma unroll
  for (int j = 0; j < 4; j++) {
    int row = m0 + hi * 4 + j;
    out[row * DOUTC + col] = acc[j] + bias;
  }
}

// ---------------- launch ----------------
static constexpr size_t AL(size_t x) { return (x + 255) & ~(size_t)255; }

extern "C" void kernel_launch(void* const* d_in, const int* in_sizes, int n_in,
                              void* d_out, int out_size, void* d_ws, size_t ws_size,
                              hipStream_t stream) {
  const float* x   = (const float*)d_in[0];
  const int*  edge = (const int*)d_in[1];
  const int*  batch= (const int*)d_in[2];
  const float* W1  = (const float*)d_in[3];
  const float* b1  = (const float*)d_in[4];
  const float* W2  = (const float*)d_in[5];
  const float* b2  = (const float*)d_in[6];
  const float* Wg1 = (const float*)d_in[7];
  const float* bg1 = (const float*)d_in[8];
  const float* Wg2 = (const float*)d_in[9];
  const float* bg2 = (const float*)d_in[10];
  float* out = (float*)d_out;
  const int* src = edge;
  const int* dst = edge + N_EDGESC;

  size_t o = 0;
  size_t OFF_AGG = o;  o += AL((size_t)N_NODES * DIN * 4);   // agg f32; later pooling partials
  size_t OFF_H1  = o;  o += AL((size_t)N_NODES * DIN * 2);   // h1b bf16
  size_t OFF_AGB = o;  o += AL((size_t)N_NODES * 96 * 2);    // xb (stride 84) then aggb (stride 96)
  size_t OFF_CSR = o;  o += AL((size_t)N_EDGESC * 4);
  size_t OFF_W2T = o;  o += AL((size_t)896 * 96 * 2);
  size_t OFF_W1H = o;  o += AL((size_t)96 * 96 * 2);
  size_t OFF_W1L = o;  o += AL((size_t)96 * 96 * 2);
  size_t OFF_G1H = o;  o += AL((size_t)DF1 * KP1 * 2);
  size_t OFF_G1L = o;  o += AL((size_t)DF1 * KP1 * 2);
  size_t OFF_G2H = o;  o += AL((size_t)DOUTC * DF1 * 2);
  size_t OFF_G2L = o;  o += AL((size_t)DOUTC * DF1 * 2);
  size_t OFF_ZH  = o;  o += AL((size_t)NGRAPH * KP1 * 2);
  size_t OFF_ZL  = o;  o += AL((size_t)NGRAPH * KP1 * 2);
  size_t OFF_Z1H = o;  o += AL((size_t)NGRAPH * DF1 * 2);
  size_t OFF_Z1L = o;  o += AL((size_t)NGRAPH * DF1 * 2);
  size_t OFF_RP  = o;  o += AL((size_t)(N_NODES + 1) * 4);
  size_t OFF_CUR = o;  o += AL((size_t)N_NODES * 4);
  size_t OFF_BS  = o;  o += AL(128 * 4);
  size_t OFF_BO  = o;  o += AL(128 * 4);
  size_t OFF_DEG = o;  o += AL((size_t)N_NODES * 4);          // zero region starts here
  size_t OFF_MAX = o;  o += AL((size_t)NGRAPH * DHID * 4);
  size_t OFF_SUM = o;  o += AL((size_t)NGRAPH * DHID * 4);
  size_t OFF_CNT = o;  o += AL(NGRAPH * 4);
  size_t TOTAL = o;
  size_t ZERO0 = OFF_DEG, ZEROB = TOTAL - OFF_DEG;
  if (ws_size < TOTAL) return;

  // pooling partials alias the agg region (agg dead after k_conv1m)
  size_t PB = AL((size_t)PBLK2 * DHID * 4);
  size_t OFF_PM0 = OFF_AGG;
  size_t OFF_PS0 = OFF_AGG + PB;
  size_t OFF_PM1 = OFF_AGG + 2 * PB;
  size_t OFF_PS1 = OFF_AGG + 3 * PB;
  size_t OFF_BLG = OFF_AGG + 4 * PB;

  char* ws = (char*)d_ws;
  float* agg = (float*)(ws + OFF_AGG);
  unsigned short* h1b = (unsigned short*)(ws + OFF_H1);
  unsigned short* aggb = (unsigned short*)(ws + OFF_AGB);
  unsigned short* xb   = (unsigned short*)(ws + OFF_AGB);   // alias: xb dead before aggb written
  int* csr   = (int*)(ws + OFF_CSR);
  unsigned short* w2t = (unsigned short*)(ws + OFF_W2T);
  unsigned short* w1h = (unsigned short*)(ws + OFF_W1H);
  unsigned short* w1l = (unsigned short*)(ws + OFF_W1L);
  unsigned short* g1h = (unsigned short*)(ws + OFF_G1H);
  unsigned short* g1l = (unsigned short*)(ws + OFF_G1L);
  unsigned short* g2h = (unsigned short*)(ws + OFF_G2H);
  unsigned short* g2l = (unsigned short*)(ws + OFF_G2L);
  unsigned short* zh  = (unsigned short*)(ws + OFF_ZH);
  unsigned short* zl  = (unsigned short*)(ws + OFF_ZL);
  unsigned short* z1h = (unsigned short*)(ws + OFF_Z1H);
  unsigned short* z1l = (unsigned short*)(ws + OFF_Z1L);
  int* rowptr = (int*)(ws + OFF_RP);
  int* cursor = (int*)(ws + OFF_CUR);
  int* bsum  = (int*)(ws + OFF_BS);
  int* boff  = (int*)(ws + OFF_BO);
  int* deg   = (int*)(ws + OFF_DEG);
  int* maxb  = (int*)(ws + OFF_MAX);
  float* sump= (float*)(ws + OFF_SUM);
  int* cnt   = (int*)(ws + OFF_CNT);
  int* pm0   = (int*)(ws + OFF_PM0);
  float* ps0 = (float*)(ws + OFF_PS0);
  int* pm1   = (int*)(ws + OFF_PM1);
  float* ps1 = (float*)(ws + OFF_PS1);
  int* blkg  = (int*)(ws + OFF_BLG);

  hipMemsetAsync(ws + ZERO0, 0, ZEROB, stream);

  k_w2t<<<(896 * 96 + 255) / 256, 256, 0, stream>>>(W2, w2t);
  k_w1t<<<(96 * 96 + 255) / 256, 256, 0, stream>>>(W1, w1h, w1l);
  k_wsplit<2 * DHID, KP1, DF1><<<(KP1 / 32) * (DF1 / 32), 256, 0, stream>>>(Wg1, g1h, g1l);
  k_wsplit<DF1, DF1, DOUTC><<<(DF1 / 32) * (DOUTC / 32), 256, 0, stream>>>(Wg2, g2h, g2l);
  k_xbf<<<(N_NODES * DIN / 8 + 255) / 256, 256, 0, stream>>>(x, xb);
  k_deg<<<N_EDGESC / 256, 256, 0, stream>>>(dst, deg);
  k_scan1<<<SBLOCKS, 256, 0, stream>>>(deg, bsum);
  k_scan2<<<1, 128, 0, stream>>>(bsum, boff);
  k_scan3<<<SBLOCKS, 256, 0, stream>>>(deg, boff, rowptr, cursor);
  k_fill<<<N_EDGESC / 256, 256, 0, stream>>>(src, dst, cursor, csr);
  k_counts<<<(N_NODES + 2047) / 2048, 256, 0, stream>>>(batch, cnt);

  k_agg1b<<<(N_NODES + 7) / 8, 256, 0, stream>>>(xb, rowptr, csr, agg);
  k_conv1m<<<(N_NODES + 63) / 64, 256, 0, stream>>>(agg, w1h, w1l, b1, h1b);
  k_agg2<<<(N_NODES + 7) / 8, 256, 0, stream>>>(h1b, rowptr, csr, aggb);
  k_conv2pool3<<<PBLK2, 256, 0, stream>>>(aggb, w2t, b2, batch, pm0, ps0, pm1, ps1, blkg, maxb, sump);
  k_pool2<<<NGRAPH, 256, 0, stream>>>(pm0, ps0, pm1, ps1, blkg, cnt, maxb, sump, zh, zl);

  k_mlp1m<<<(DF1 / 16) * 2, 256, 0, stream>>>(zh, zl, g1h, g1l, bg1, z1h, z1l);
  k_mlp2m<<<(DOUTC / 16) * 2, 256, 0, stream>>>(z1h, z1l, g2h, g2l, bg2, out);
}

// Round 7
// 286.208 us; speedup vs baseline: 2.0036x; 1.1751x over previous
//
#include <hip/hip_runtime.h>

#define N_NODES 100000
#define N_EDGESC 800000
#define NGRAPH 128
#define DIN 84
#define DHID 840
#define DF1 1024
#define DOUTC 384
#define PBLK2 782   // ceil(N_NODES/128)
#define KP1 1696    // 2*DHID padded to x32
#define NBUCK 391   // ceil(N_NODES/256)
#define EPB 8192    // edges per bucketing block (grid 98)
#define XSTR 96     // padded row stride for xb / h1b (192B = 3 aligned lines)

typedef __attribute__((ext_vector_type(4))) float f32x4;
typedef __attribute__((ext_vector_type(8))) short bf16x8;

__device__ __forceinline__ unsigned short f2bf(float f) {
  union { float f; unsigned int u; } v; v.f = f;
  unsigned int r = v.u + 0x7FFFu + ((v.u >> 16) & 1u);
  return (unsigned short)(r >> 16);
}
__device__ __forceinline__ float bf2f(unsigned short h) {
  union { unsigned int u; float f; } v; v.u = ((unsigned int)h) << 16;
  return v.f;
}

// ---------------- bucketed CSR build ----------------
// bucket b = dst>>8 (256 nodes per bucket). Stage 1: global bucket histogram.
__global__ __launch_bounds__(256) void k_bhist(const int* __restrict__ dst, int* __restrict__ bcnt) {
  __shared__ int h[NBUCK];
  int t = threadIdx.x;
  for (int i = t; i < NBUCK; i += 256) h[i] = 0;
  __syncthreads();
  int base = blockIdx.x * EPB;
  int e1 = min(base + EPB, N_EDGESC);
  for (int e = base + t; e < e1; e += 256)
    atomicAdd(&h[dst[e] >> 8], 1);
  __syncthreads();
  for (int i = t; i < NBUCK; i += 256) if (h[i]) atomicAdd(&bcnt[i], h[i]);
}

// Stage 2: exclusive scan over 391 buckets -> boff (392 entries) + cursor init.
__global__ __launch_bounds__(512) void k_bscan(const int* __restrict__ bcnt, int* __restrict__ boff,
                                               int* __restrict__ bcur) {
  __shared__ int sd[512];
  int t = threadIdx.x;
  int v = (t < NBUCK) ? bcnt[t] : 0;
  sd[t] = v; __syncthreads();
  for (int off = 1; off < 512; off <<= 1) {
    int add = (t >= off) ? sd[t - off] : 0;
    __syncthreads();
    sd[t] += add;
    __syncthreads();
  }
  if (t <= NBUCK) {
    boff[t] = sd[t] - v;       // t==NBUCK: v=0 -> total = N_EDGESC
    if (t < NBUCK) bcur[t] = sd[t] - v;
  }
}

// Stage 3: scatter edges into bucket-contiguous record array, packed (dstLocal<<24)|src.
// Per-block LDS histogram + one global atomicAdd per (block,bucket) -> dense chunked writes.
__global__ __launch_bounds__(256) void k_bfill(const int* __restrict__ src, const int* __restrict__ dst,
                                               int* __restrict__ bcur, unsigned int* __restrict__ rec) {
  __shared__ int hcnt[NBUCK];
  __shared__ int hbase[NBUCK];
  int t = threadIdx.x;
  int e0 = blockIdx.x * EPB;
  int e1 = min(e0 + EPB, N_EDGESC);
  for (int i = t; i < NBUCK; i += 256) hcnt[i] = 0;
  __syncthreads();
  for (int e = e0 + t; e < e1; e += 256)
    atomicAdd(&hcnt[dst[e] >> 8], 1);
  __syncthreads();
  for (int i = t; i < NBUCK; i += 256) {
    int c = hcnt[i];
    hbase[i] = c ? atomicAdd(&bcur[i], c) : 0;
  }
  __syncthreads();
  for (int i = t; i < NBUCK; i += 256) hcnt[i] = 0;
  __syncthreads();
  for (int e = e0 + t; e < e1; e += 256) {
    int d = dst[e];
    int b = d >> 8;
    int r = atomicAdd(&hcnt[b], 1);
    rec[hbase[b] + r] = ((unsigned int)(d & 255) << 24) | (unsigned int)src[e];
  }
}

// Stage 4: per-bucket counting sort -> rowptr (coalesced) + csr (scatter confined to 8KB window).
__global__ __launch_bounds__(256) void k_bsort(const unsigned int* __restrict__ rec, const int* __restrict__ boff,
                                               int* __restrict__ rowptr, int* __restrict__ csr) {
  __shared__ int lcnt[256];
  __shared__ int lcur[256];
  int b = blockIdx.x, t = threadIdx.x;
  int e0 = boff[b], e1 = boff[b + 1];
  lcnt[t] = 0;
  __syncthreads();
  for (int i = e0 + t; i < e1; i += 256) atomicAdd(&lcnt[rec[i] >> 24], 1);
  __syncthreads();
  int v = lcnt[t];
  for (int off = 1; off < 256; off <<= 1) {
    int add = (t >= off) ? lcnt[t - off] : 0;
    __syncthreads();
    lcnt[t] += add;
    __syncthreads();
  }
  int excl = lcnt[t] - v;
  int node = b * 256 + t;
  if (node < N_NODES) rowptr[node] = e0 + excl;
  lcur[t] = e0 + excl;
  if (b == NBUCK - 1 && t == 0) rowptr[N_NODES] = N_EDGESC;
  __syncthreads();
  for (int i = e0 + t; i < e1; i += 256) {
    unsigned int r = rec[i];
    int d = r >> 24;
    int pos = atomicAdd(&lcur[d], 1);
    csr[pos] = (int)(r & 0xFFFFFFu);
  }
}

// ---------------- per-graph node counts ----------------
__global__ __launch_bounds__(256) void k_counts(const int* __restrict__ batch, int* __restrict__ cnt) {
  __shared__ int h[NGRAPH];
  int t = threadIdx.x;
  if (t < NGRAPH) h[t] = 0;
  __syncthreads();
  int base = blockIdx.x * 2048;
  for (int j = 0; j < 8; j++) {
    int i = base + j * 256 + t;
    if (i < N_NODES) atomicAdd(&h[batch[i]], 1);
  }
  __syncthreads();
  if (t < NGRAPH && h[t] > 0) atomicAdd(&cnt[t], h[t]);
}

// ---------------- x -> bf16, padded row stride 96 (192B = 3 aligned lines) ----------------
__global__ __launch_bounds__(256) void k_xbf(const float* __restrict__ x, unsigned short* __restrict__ xb) {
  int idx = blockIdx.x * 256 + threadIdx.x;   // one uint2 (4 bf16) per thread
  if (idx >= N_NODES * 24) return;
  int r = idx / 24, c = idx - r * 24;
  uint2 p = {0u, 0u};
  if (c < 21) {
    f32x4 v = *(const f32x4*)&x[r * DIN + c * 4];
    p.x = (unsigned int)f2bf(v.x) | ((unsigned int)f2bf(v.y) << 16);
    p.y = (unsigned int)f2bf(v.z) | ((unsigned int)f2bf(v.w) << 16);
  }
  *(uint2*)&xb[r * XSTR + c * 4] = p;
}

__device__ __forceinline__ f32x4 bfq(uint2 p) {
  f32x4 r;
  r.x = bf2f((unsigned short)(p.x & 0xffff)); r.y = bf2f((unsigned short)(p.x >> 16));
  r.z = bf2f((unsigned short)(p.y & 0xffff)); r.w = bf2f((unsigned short)(p.y >> 16));
  return r;
}

// ---------------- agg1: bf16 gather (stride 96), f32 out (stride 84) ----------------
__global__ __launch_bounds__(256) void k_agg1b(const unsigned short* __restrict__ xb, const int* __restrict__ rowptr,
                                               const int* __restrict__ csr, float* __restrict__ out) {
  int node = blockIdx.x * 8 + (threadIdx.x >> 5);
  int lane = threadIdx.x & 31;
  if (node >= N_NODES) return;
  int r0 = rowptr[node], r1 = rowptr[node + 1];
  bool act = lane < 21;
  f32x4 a = {0.f, 0.f, 0.f, 0.f};
  if (act) a = bfq(*(const uint2*)&xb[node * XSTR + lane * 4]);
  int e = r0;
  for (; e + 4 <= r1; e += 4) {
    int s0 = csr[e], s1 = csr[e + 1], s2 = csr[e + 2], s3 = csr[e + 3];
    if (act) {
      uint2 q0 = *(const uint2*)&xb[s0 * XSTR + lane * 4];
      uint2 q1 = *(const uint2*)&xb[s1 * XSTR + lane * 4];
      uint2 q2 = *(const uint2*)&xb[s2 * XSTR + lane * 4];
      uint2 q3 = *(const uint2*)&xb[s3 * XSTR + lane * 4];
      a += (bfq(q0) + bfq(q1)) + (bfq(q2) + bfq(q3));
    }
  }
  for (; e < r1; e++) {
    int s = csr[e];
    if (act) a += bfq(*(const uint2*)&xb[s * XSTR + lane * 4]);
  }
  if (act) ((f32x4*)out)[node * 21 + lane] = a;
}

// ---------------- agg2: bf16 in (stride 96), bf16 out (stride 96, zero-pad) ----------------
__global__ __launch_bounds__(256) void k_agg2(const unsigned short* __restrict__ h1b, const int* __restrict__ rowptr,
                                              const int* __restrict__ csr, unsigned short* __restrict__ out) {
  int node = blockIdx.x * 8 + (threadIdx.x >> 5);
  int lane = threadIdx.x & 31;
  if (node >= N_NODES) return;
  int r0 = rowptr[node], r1 = rowptr[node + 1];
  bool act = lane < 21;
  f32x4 a = {0.f, 0.f, 0.f, 0.f};
  if (act) a = bfq(*(const uint2*)&h1b[node * XSTR + lane * 4]);
  int e = r0;
  for (; e + 4 <= r1; e += 4) {
    int s0 = csr[e], s1 = csr[e + 1], s2 = csr[e + 2], s3 = csr[e + 3];
    if (act) {
      uint2 q0 = *(const uint2*)&h1b[s0 * XSTR + lane * 4];
      uint2 q1 = *(const uint2*)&h1b[s1 * XSTR + lane * 4];
      uint2 q2 = *(const uint2*)&h1b[s2 * XSTR + lane * 4];
      uint2 q3 = *(const uint2*)&h1b[s3 * XSTR + lane * 4];
      a += (bfq(q0) + bfq(q1)) + (bfq(q2) + bfq(q3));
    }
  }
  for (; e < r1; e++) {
    int s = csr[e];
    if (act) a += bfq(*(const uint2*)&h1b[s * XSTR + lane * 4]);
  }
  if (lane < 24) {
    uint2 p;
    if (act) {
      p.x = (unsigned int)f2bf(a.x) | ((unsigned int)f2bf(a.y) << 16);
      p.y = (unsigned int)f2bf(a.z) | ((unsigned int)f2bf(a.w) << 16);
    } else {
      p.x = 0u; p.y = 0u;   // zero K-pad cols 84..95
    }
    *(uint2*)&out[node * XSTR + lane * 4] = p;
  }
}

// ---------------- W1^T split hi/lo bf16, padded [96][96] ----------------
__global__ __launch_bounds__(256) void k_w1t(const float* __restrict__ W1, unsigned short* __restrict__ w1h,
                                             unsigned short* __restrict__ w1l) {
  int idx = blockIdx.x * 256 + threadIdx.x;
  if (idx >= 96 * 96) return;
  int n = idx / 96, k = idx % 96;
  float v = (n < DIN && k < DIN) ? W1[k * DIN + n] : 0.f;
  unsigned short h = f2bf(v);
  w1h[idx] = h;
  w1l[idx] = f2bf(v - bf2f(h));
}

// ---------------- generic W [K][N] -> transposed hi/lo bf16 [N][KP] ----------------
template <int K, int KPAD, int N>
__global__ __launch_bounds__(256) void k_wsplit(const float* __restrict__ W,
                                                unsigned short* __restrict__ wh,
                                                unsigned short* __restrict__ wl) {
  __shared__ float tile[32][33];
  int b = blockIdx.x;
  int kt = b % (KPAD / 32), nt = b / (KPAD / 32);
  int k0 = kt * 32, n0 = nt * 32;
  int t = threadIdx.x;
  int r = t >> 3, c4 = (t & 7) * 4;
  int k = k0 + r;
  f32x4 v = {0.f, 0.f, 0.f, 0.f};
  if (k < K) v = *(const f32x4*)&W[(size_t)k * N + n0 + c4];
  tile[r][c4 + 0] = v.x; tile[r][c4 + 1] = v.y; tile[r][c4 + 2] = v.z; tile[r][c4 + 3] = v.w;
  __syncthreads();
  int n = t >> 3;
  float f0 = tile[c4 + 0][n], f1 = tile[c4 + 1][n], f2 = tile[c4 + 2][n], f3 = tile[c4 + 3][n];
  unsigned short h0 = f2bf(f0), h1_ = f2bf(f1), h2_ = f2bf(f2), h3_ = f2bf(f3);
  uint2 ph, pl;
  ph.x = (unsigned int)h0 | ((unsigned int)h1_ << 16);
  ph.y = (unsigned int)h2_ | ((unsigned int)h3_ << 16);
  pl.x = (unsigned int)f2bf(f0 - bf2f(h0)) | ((unsigned int)f2bf(f1 - bf2f(h1_)) << 16);
  pl.y = (unsigned int)f2bf(f2 - bf2f(h2_)) | ((unsigned int)f2bf(f3 - bf2f(h3_)) << 16);
  *(uint2*)&wh[(size_t)(n0 + n) * KPAD + k0 + c4] = ph;
  *(uint2*)&wl[(size_t)(n0 + n) * KPAD + k0 + c4] = pl;
}

// ---------------- conv1 via MFMA, split-bf16; h1 emitted as bf16 (stride 96) ----------------
__global__ __launch_bounds__(256) void k_conv1m(const float* __restrict__ agg,
                                                const unsigned short* __restrict__ w1h,
                                                const unsigned short* __restrict__ w1l,
                                                const float* __restrict__ b1,
                                                unsigned short* __restrict__ h1b) {
  constexpr int LDA = 104;
  __shared__ __align__(16) unsigned short Ah[64 * LDA];
  __shared__ __align__(16) unsigned short Al[64 * LDA];
  int t = threadIdx.x;
  int m0 = blockIdx.x * 64;

  for (int idx = t; idx < 64 * 21; idx += 256) {
    int r = idx / 21, c = idx - r * 21;
    int row = m0 + r;
    f32x4 v = {0.f, 0.f, 0.f, 0.f};
    if (row < N_NODES) v = *(const f32x4*)&agg[row * DIN + c * 4];
    unsigned short h0 = f2bf(v.x), h1_ = f2bf(v.y), h2_ = f2bf(v.z), h3_ = f2bf(v.w);
    unsigned short l0 = f2bf(v.x - bf2f(h0)), l1 = f2bf(v.y - bf2f(h1_));
    unsigned short l2 = f2bf(v.z - bf2f(h2_)), l3 = f2bf(v.w - bf2f(h3_));
    unsigned int* ph = (unsigned int*)&Ah[r * LDA + c * 4];
    ph[0] = (unsigned int)h0 | ((unsigned int)h1_ << 16);
    ph[1] = (unsigned int)h2_ | ((unsigned int)h3_ << 16);
    unsigned int* pl = (unsigned int*)&Al[r * LDA + c * 4];
    pl[0] = (unsigned int)l0 | ((unsigned int)l1 << 16);
    pl[1] = (unsigned int)l2 | ((unsigned int)l3 << 16);
  }
  for (int idx = t; idx < 64 * 6; idx += 256) {
    int r = idx / 6, c = idx - r * 6;
    ((unsigned int*)&Ah[r * LDA + 84])[c] = 0;
    ((unsigned int*)&Al[r * LDA + 84])[c] = 0;
  }
  __syncthreads();

  int w = t >> 6, l = t & 63;
  int lr = l & 15, lk = (l >> 4) * 8;
  bf16x8 ah[3], al[3];
  #pragma unroll
  for (int kk = 0; kk < 3; kk++) {
    ah[kk] = *(bf16x8*)&Ah[(w * 16 + lr) * LDA + lk + kk * 32];
    al[kk] = *(bf16x8*)&Al[(w * 16 + lr) * LDA + lk + kk * 32];
  }

  #pragma unroll
  for (int nt = 0; nt < 6; nt++) {
    f32x4 acc = {0.f, 0.f, 0.f, 0.f};
    #pragma unroll
    for (int kk = 0; kk < 3; kk++) {
      bf16x8 bh = *(const bf16x8*)&w1h[(nt * 16 + lr) * 96 + lk + kk * 32];
      bf16x8 bl = *(const bf16x8*)&w1l[(nt * 16 + lr) * 96 + lk + kk * 32];
      acc = __builtin_amdgcn_mfma_f32_16x16x32_bf16(ah[kk], bh, acc, 0, 0, 0);
      acc = __builtin_amdgcn_mfma_f32_16x16x32_bf16(al[kk], bh, acc, 0, 0, 0);
      acc = __builtin_amdgcn_mfma_f32_16x16x32_bf16(ah[kk], bl, acc, 0, 0, 0);
    }
    int col = nt * 16 + lr;
    if (col < DIN) {
      float bias = b1[col];
      int rbase = m0 + w * 16 + (l >> 4) * 4;
      #pragma unroll
      for (int j = 0; j < 4; j++) {
        if (rbase + j < N_NODES)
          h1b[(rbase + j) * XSTR + col] = f2bf(fmaxf(acc[j] + bias, 0.f));
      }
    }
  }
}

// ---------------- W2^T in bf16, padded [896][96] ----------------
__global__ __launch_bounds__(256) void k_w2t(const float* __restrict__ W2, unsigned short* __restrict__ w2t) {
  int idx = blockIdx.x * 256 + threadIdx.x;
  if (idx >= 896 * 96) return;
  int n = idx / 96, k = idx % 96;
  float v = (n < DHID && k < DIN) ? W2[k * DHID + n] : 0.f;
  w2t[idx] = f2bf(v);
}

// ---------------- conv2 + pooling stage 1: 128-row blocks, uniform fast path ----------
__global__ __launch_bounds__(256) void k_conv2pool3(const unsigned short* __restrict__ aggb,
                                                    const unsigned short* __restrict__ w2t,
                                                    const float* __restrict__ b2,
                                                    const int* __restrict__ batch,
                                                    int* __restrict__ pm0, float* __restrict__ ps0,
                                                    int* __restrict__ pm1, float* __restrict__ ps1,
                                                    int* __restrict__ blkg,
                                                    int* __restrict__ maxb, float* __restrict__ sump) {
  __shared__ int   smax0[DHID]; __shared__ float ssum0[DHID];
  __shared__ int   smax1[DHID]; __shared__ float ssum1[DHID];
  int t = threadIdx.x;
  int w = t >> 6, l = t & 63;
  int b = blockIdx.x;
  int m0 = b * 128;
  int r0 = m0 + (w & 1) * 64;
  int lr = l & 15, hi = l >> 4, lk = hi * 8;

  for (int i = t; i < DHID; i += 256) { smax0[i] = 0; ssum0[i] = 0.f; smax1[i] = 0; ssum1[i] = 0.f; }

  bf16x8 afr[4][3];
  #pragma unroll
  for (int rg = 0; rg < 4; rg++) {
    int row = r0 + rg * 16 + lr;
    #pragma unroll
    for (int kk = 0; kk < 3; kk++) {
      bf16x8 v = {0, 0, 0, 0, 0, 0, 0, 0};
      if (row < N_NODES) v = *(const bf16x8*)&aggb[row * XSTR + lk + kk * 32];
      afr[rg][kk] = v;
    }
  }

  int g0 = batch[m0];
  int g1 = batch[min(m0 + 127, N_NODES - 1)];
  bool fast = (g0 == g1) && (m0 + 127 < N_NODES);
  __syncthreads();

  if (fast) {
    for (int nc = (w >> 1); nc < 14; nc += 2) {
      #pragma unroll
      for (int nt = 0; nt < 4; nt++) {
        int c = nc * 64 + nt * 16 + lr;
        const unsigned short* bp = &w2t[(nc * 64 + nt * 16 + lr) * 96 + lk];
        bf16x8 b0v = *(const bf16x8*)(bp);
        bf16x8 b1v = *(const bf16x8*)(bp + 32);
        bf16x8 b2v = *(const bf16x8*)(bp + 64);
        float bias = (c < DHID) ? b2[c] : 0.f;
        float mx = 0.f, sm = 0.f;
        #pragma unroll
        for (int rg = 0; rg < 4; rg++) {
          f32x4 a_ = {0.f, 0.f, 0.f, 0.f};
          a_ = __builtin_amdgcn_mfma_f32_16x16x32_bf16(afr[rg][0], b0v, a_, 0, 0, 0);
          a_ = __builtin_amdgcn_mfma_f32_16x16x32_bf16(afr[rg][1], b1v, a_, 0, 0, 0);
          a_ = __builtin_amdgcn_mfma_f32_16x16x32_bf16(afr[rg][2], b2v, a_, 0, 0, 0);
          #pragma unroll
          for (int j = 0; j < 4; j++) {
            float v = fmaxf(a_[j] + bias, 0.f);
            mx = fmaxf(mx, v); sm += v;
          }
        }
        mx = fmaxf(mx, __shfl_xor(mx, 16)); sm += __shfl_xor(sm, 16);
        mx = fmaxf(mx, __shfl_xor(mx, 32)); sm += __shfl_xor(sm, 32);
        if (hi == 0 && c < DHID) {
          atomicMax(&smax0[c], __float_as_int(mx));
          atomicAdd(&ssum0[c], sm);
        }
      }
    }
  } else {
    int grow[4][4];
    #pragma unroll
    for (int rg = 0; rg < 4; rg++)
      #pragma unroll
      for (int j = 0; j < 4; j++) {
        int row = r0 + rg * 16 + hi * 4 + j;
        grow[rg][j] = (row < N_NODES) ? batch[row] : -1;
      }
    for (int nc = (w >> 1); nc < 14; nc += 2) {
      #pragma unroll
      for (int nt = 0; nt < 4; nt++) {
        int c = nc * 64 + nt * 16 + lr;
        const unsigned short* bp = &w2t[(nc * 64 + nt * 16 + lr) * 96 + lk];
        bf16x8 b0v = *(const bf16x8*)(bp);
        bf16x8 b1v = *(const bf16x8*)(bp + 32);
        bf16x8 b2v = *(const bf16x8*)(bp + 64);
        float bias = (c < DHID) ? b2[c] : 0.f;
        float mx0 = 0.f, sm0 = 0.f, mx1 = 0.f, sm1 = 0.f;
        float vv[4][4];
        #pragma unroll
        for (int rg = 0; rg < 4; rg++) {
          f32x4 a_ = {0.f, 0.f, 0.f, 0.f};
          a_ = __builtin_amdgcn_mfma_f32_16x16x32_bf16(afr[rg][0], b0v, a_, 0, 0, 0);
          a_ = __builtin_amdgcn_mfma_f32_16x16x32_bf16(afr[rg][1], b1v, a_, 0, 0, 0);
          a_ = __builtin_amdgcn_mfma_f32_16x16x32_bf16(afr[rg][2], b2v, a_, 0, 0, 0);
          #pragma unroll
          for (int j = 0; j < 4; j++) {
            float v = fmaxf(a_[j] + bias, 0.f);
            vv[rg][j] = v;
            if (grow[rg][j] == g0) { mx0 = fmaxf(mx0, v); sm0 += v; }
            if (grow[rg][j] == g1) { mx1 = fmaxf(mx1, v); sm1 += v; }
          }
        }
        mx0 = fmaxf(mx0, __shfl_xor(mx0, 16)); sm0 += __shfl_xor(sm0, 16);
        mx0 = fmaxf(mx0, __shfl_xor(mx0, 32)); sm0 += __shfl_xor(sm0, 32);
        mx1 = fmaxf(mx1, __shfl_xor(mx1, 16)); sm1 += __shfl_xor(sm1, 16);
        mx1 = fmaxf(mx1, __shfl_xor(mx1, 32)); sm1 += __shfl_xor(sm1, 32);
        if (hi == 0 && c < DHID) {
          atomicMax(&smax0[c], __float_as_int(mx0));
          atomicAdd(&ssum0[c], sm0);
          atomicMax(&smax1[c], __float_as_int(mx1));
          atomicAdd(&ssum1[c], sm1);
        }
        if (g1 - g0 >= 2) {
          for (int g = g0 + 1; g < g1; g++) {
            float mx = 0.f, sm = 0.f;
            #pragma unroll
            for (int rg = 0; rg < 4; rg++)
              #pragma unroll
              for (int j = 0; j < 4; j++)
                if (grow[rg][j] == g) { mx = fmaxf(mx, vv[rg][j]); sm += vv[rg][j]; }
            mx = fmaxf(mx, __shfl_xor(mx, 16)); sm += __shfl_xor(sm, 16);
            mx = fmaxf(mx, __shfl_xor(mx, 32)); sm += __shfl_xor(sm, 32);
            if (hi == 0 && c < DHID) {
              atomicMax(&maxb[g * DHID + c], __float_as_int(mx));
              atomicAdd(&sump[g * DHID + c], sm);
            }
          }
        }
      }
    }
  }
  __syncthreads();
  for (int i = t; i < DHID; i += 256) {
    pm0[b * DHID + i] = smax0[i];
    ps0[b * DHID + i] = ssum0[i];
  }
  if (g0 != g1) {
    for (int i = t; i < DHID; i += 256) {
      pm1[b * DHID + i] = smax1[i];
      ps1[b * DHID + i] = ssum1[i];
    }
  }
  if (t == 0) { blkg[b * 2] = g0; blkg[b * 2 + 1] = g1; }
}

// ---------------- pooling stage 2: merge partials, emit z as hi/lo bf16 [128][KP1] --------
__global__ __launch_bounds__(256) void k_pool2(const int* __restrict__ pm0, const float* __restrict__ ps0,
                                               const int* __restrict__ pm1, const float* __restrict__ ps1,
                                               const int* __restrict__ blkg, const int* __restrict__ cnt,
                                               const int* __restrict__ maxb, const float* __restrict__ sump,
                                               unsigned short* __restrict__ zh, unsigned short* __restrict__ zl) {
  __shared__ int sstart[NGRAPH];
  int g = blockIdx.x, t = threadIdx.x;
  if (t == 0) {
    int s = 0;
    for (int i = 0; i < NGRAPH; i++) { sstart[i] = s; s += cnt[i]; }
  }
  __syncthreads();
  int c0 = cnt[g];
  int ns = sstart[g], ne = ns + c0;
  int b0 = ns / 128, b1 = (c0 > 0) ? (ne - 1) / 128 : b0 - 1;
  for (int c = t; c < DHID; c += 256) {
    float mx = __int_as_float(maxb[g * DHID + c]);
    float sm = sump[g * DHID + c];
    for (int b = b0; b <= b1; b++) {
      int gg0 = blkg[2 * b], gg1 = blkg[2 * b + 1];
      if (gg0 == g)      { mx = fmaxf(mx, __int_as_float(pm0[b * DHID + c])); sm += ps0[b * DHID + c]; }
      else if (gg1 == g) { mx = fmaxf(mx, __int_as_float(pm1[b * DHID + c])); sm += ps1[b * DHID + c]; }
    }
    float vmax = (c0 > 0) ? mx : 0.f;
    float vmean = sm / (float)max(c0, 1);
    unsigned short hm = f2bf(vmax);
    zh[g * KP1 + c] = hm;
    zl[g * KP1 + c] = f2bf(vmax - bf2f(hm));
    unsigned short he = f2bf(vmean);
    zh[g * KP1 + DHID + c] = he;
    zl[g * KP1 + DHID + c] = f2bf(vmean - bf2f(he));
  }
  if (t < KP1 - 2 * DHID) {  // zero K-pad 1680..1695
    zh[g * KP1 + 2 * DHID + t] = 0;
    zl[g * KP1 + 2 * DHID + t] = 0;
  }
}

// ---------------- MLP1: z1 = relu(z @ Wg1 + bg1), split-bf16 MFMA, hi/lo out ----------------
__global__ __launch_bounds__(256) void k_mlp1m(const unsigned short* __restrict__ zh, const unsigned short* __restrict__ zl,
                                               const unsigned short* __restrict__ wh, const unsigned short* __restrict__ wl,
                                               const float* __restrict__ bg,
                                               unsigned short* __restrict__ z1h, unsigned short* __restrict__ z1l) {
  int t = threadIdx.x, w = t >> 6, l = t & 63;
  int lr = l & 15, hi = l >> 4, lk = hi * 8;
  int b = blockIdx.x;
  int n0 = (b >> 1) * 16;
  int m0 = (b & 1) * 64 + w * 16;
  const unsigned short* za = &zh[(size_t)(m0 + lr) * KP1 + lk];
  const unsigned short* zb = &zl[(size_t)(m0 + lr) * KP1 + lk];
  const unsigned short* wa = &wh[(size_t)(n0 + lr) * KP1 + lk];
  const unsigned short* wb = &wl[(size_t)(n0 + lr) * KP1 + lk];
  f32x4 acc = {0.f, 0.f, 0.f, 0.f};
  for (int ks = 0; ks < KP1 / 32; ks++) {
    bf16x8 ah = *(const bf16x8*)(za + ks * 32);
    bf16x8 al = *(const bf16x8*)(zb + ks * 32);
    bf16x8 bh = *(const bf16x8*)(wa + ks * 32);
    bf16x8 bl = *(const bf16x8*)(wb + ks * 32);
    acc = __builtin_amdgcn_mfma_f32_16x16x32_bf16(ah, bh, acc, 0, 0, 0);
    acc = __builtin_amdgcn_mfma_f32_16x16x32_bf16(al, bh, acc, 0, 0, 0);
    acc = __builtin_amdgcn_mfma_f32_16x16x32_bf16(ah, bl, acc, 0, 0, 0);
  }
  int col = n0 + lr;
  float bias = bg[col];
  #pragma unroll
  for (int j = 0; j < 4; j++) {
    int row = m0 + hi * 4 + j;
    float v = fmaxf(acc[j] + bias, 0.f);
    unsigned short h = f2bf(v);
    z1h[row * DF1 + col] = h;
    z1l[row * DF1 + col] = f2bf(v - bf2f(h));
  }
}

// ---------------- MLP2: out = z1 @ Wg2 + bg2, split-bf16 MFMA, f32 out ----------------
__global__ __launch_bounds__(256) void k_mlp2m(const unsigned short* __restrict__ z1h, const unsigned short* __restrict__ z1l,
                                               const unsigned short* __restrict__ wh, const unsigned short* __restrict__ wl,
                                               const float* __restrict__ bg, float* __restrict__ out) {
  int t = threadIdx.x, w = t >> 6, l = t & 63;
  int lr = l & 15, hi = l >> 4, lk = hi * 8;
  int b = blockIdx.x;
  int n0 = (b >> 1) * 16;
  int m0 = (b & 1) * 64 + w * 16;
  const unsigned short* za = &z1h[(size_t)(m0 + lr) * DF1 + lk];
  const unsigned short* zb = &z1l[(size_t)(m0 + lr) * DF1 + lk];
  const unsigned short* wa = &wh[(size_t)(n0 + lr) * DF1 + lk];
  const unsigned short* wb = &wl[(size_t)(n0 + lr) * DF1 + lk];
  f32x4 acc = {0.f, 0.f, 0.f, 0.f};
  for (int ks = 0; ks < DF1 / 32; ks++) {
    bf16x8 ah = *(const bf16x8*)(za + ks * 32);
    bf16x8 al = *(const bf16x8*)(zb + ks * 32);
    bf16x8 bh = *(const bf16x8*)(wa + ks * 32);
    bf16x8 bl = *(const bf16x8*)(wb + ks * 32);
    acc = __builtin_amdgcn_mfma_f32_16x16x32_bf16(ah, bh, acc, 0, 0, 0);
    acc = __builtin_amdgcn_mfma_f32_16x16x32_bf16(al, bh, acc, 0, 0, 0);
    acc = __builtin_amdgcn_mfma_f32_16x16x32_bf16(ah, bl, acc, 0, 0, 0);
  }
  int col = n0 + lr;
  float bias = bg[col];
  #pragma unroll
  for (int j = 0; j < 4; j++) {
    int row = m0 + hi * 4 + j;
    out[row * DOUTC + col] = acc[j] + bias;
  }
}

// ---------------- launch ----------------
static constexpr size_t AL(size_t x) { return (x + 255) & ~(size_t)255; }

extern "C" void kernel_launch(void* const* d_in, const int* in_sizes, int n_in,
                              void* d_out, int out_size, void* d_ws, size_t ws_size,
                              hipStream_t stream) {
  const float* x   = (const float*)d_in[0];
  const int*  edge = (const int*)d_in[1];
  const int*  batch= (const int*)d_in[2];
  const float* W1  = (const float*)d_in[3];
  const float* b1  = (const float*)d_in[4];
  const float* W2  = (const float*)d_in[5];
  const float* b2  = (const float*)d_in[6];
  const float* Wg1 = (const float*)d_in[7];
  const float* bg1 = (const float*)d_in[8];
  const float* Wg2 = (const float*)d_in[9];
  const float* bg2 = (const float*)d_in[10];
  float* out = (float*)d_out;
  const int* src = edge;
  const int* dst = edge + N_EDGESC;

  size_t o = 0;
  size_t OFF_AGG = o;  o += AL((size_t)N_NODES * DIN * 4);    // agg f32; later pooling partials
  size_t OFF_H1  = o;  o += AL((size_t)N_NODES * XSTR * 2);   // h1b bf16, stride 96
  size_t OFF_AGB = o;  o += AL((size_t)N_NODES * XSTR * 2);   // xb then aggb (both stride 96)
  size_t OFF_CSR = o;  o += AL((size_t)N_EDGESC * 4);
  size_t OFF_REC = o;  o += AL((size_t)N_EDGESC * 4);         // bucketed edge records
  size_t OFF_W2T = o;  o += AL((size_t)896 * 96 * 2);
  size_t OFF_W1H = o;  o += AL((size_t)96 * 96 * 2);
  size_t OFF_W1L = o;  o += AL((size_t)96 * 96 * 2);
  size_t OFF_G1H = o;  o += AL((size_t)DF1 * KP1 * 2);
  size_t OFF_G1L = o;  o += AL((size_t)DF1 * KP1 * 2);
  size_t OFF_G2H = o;  o += AL((size_t)DOUTC * DF1 * 2);
  size_t OFF_G2L = o;  o += AL((size_t)DOUTC * DF1 * 2);
  size_t OFF_ZH  = o;  o += AL((size_t)NGRAPH * KP1 * 2);
  size_t OFF_ZL  = o;  o += AL((size_t)NGRAPH * KP1 * 2);
  size_t OFF_Z1H = o;  o += AL((size_t)NGRAPH * DF1 * 2);
  size_t OFF_Z1L = o;  o += AL((size_t)NGRAPH * DF1 * 2);
  size_t OFF_RP  = o;  o += AL((size_t)(N_NODES + 1) * 4);
  size_t OFF_BOF = o;  o += AL((NBUCK + 1) * 4);
  size_t OFF_BCU = o;  o += AL(NBUCK * 4);
  size_t OFF_BC  = o;  o += AL(NBUCK * 4);                    // zero region starts here
  size_t OFF_MAX = o;  o += AL((size_t)NGRAPH * DHID * 4);
  size_t OFF_SUM = o;  o += AL((size_t)NGRAPH * DHID * 4);
  size_t OFF_CNT = o;  o += AL(NGRAPH * 4);
  size_t TOTAL = o;
  size_t ZERO0 = OFF_BC, ZEROB = TOTAL - OFF_BC;
  if (ws_size < TOTAL) return;

  // pooling partials alias the agg region (agg dead after k_conv1m)
  size_t PB = AL((size_t)PBLK2 * DHID * 4);
  size_t OFF_PM0 = OFF_AGG;
  size_t OFF_PS0 = OFF_AGG + PB;
  size_t OFF_PM1 = OFF_AGG + 2 * PB;
  size_t OFF_PS1 = OFF_AGG + 3 * PB;
  size_t OFF_BLG = OFF_AGG + 4 * PB;

  char* ws = (char*)d_ws;
  float* agg = (float*)(ws + OFF_AGG);
  unsigned short* h1b = (unsigned short*)(ws + OFF_H1);
  unsigned short* aggb = (unsigned short*)(ws + OFF_AGB);
  unsigned short* xb   = (unsigned short*)(ws + OFF_AGB);   // alias: xb dead before aggb written
  int* csr   = (int*)(ws + OFF_CSR);
  unsigned int* rec = (unsigned int*)(ws + OFF_REC);
  unsigned short* w2t = (unsigned short*)(ws + OFF_W2T);
  unsigned short* w1h = (unsigned short*)(ws + OFF_W1H);
  unsigned short* w1l = (unsigned short*)(ws + OFF_W1L);
  unsigned short* g1h = (unsigned short*)(ws + OFF_G1H);
  unsigned short* g1l = (unsigned short*)(ws + OFF_G1L);
  unsigned short* g2h = (unsigned short*)(ws + OFF_G2H);
  unsigned short* g2l = (unsigned short*)(ws + OFF_G2L);
  unsigned short* zh  = (unsigned short*)(ws + OFF_ZH);
  unsigned short* zl  = (unsigned short*)(ws + OFF_ZL);
  unsigned short* z1h = (unsigned short*)(ws + OFF_Z1H);
  unsigned short* z1l = (unsigned short*)(ws + OFF_Z1L);
  int* rowptr = (int*)(ws + OFF_RP);
  int* boff  = (int*)(ws + OFF_BOF);
  int* bcur  = (int*)(ws + OFF_BCU);
  int* bcnt  = (int*)(ws + OFF_BC);
  int* maxb  = (int*)(ws + OFF_MAX);
  float* sump= (float*)(ws + OFF_SUM);
  int* cnt   = (int*)(ws + OFF_CNT);
  int* pm0   = (int*)(ws + OFF_PM0);
  float* ps0 = (float*)(ws + OFF_PS0);
  int* pm1   = (int*)(ws + OFF_PM1);
  float* ps1 = (float*)(ws + OFF_PS1);
  int* blkg  = (int*)(ws + OFF_BLG);

  hipMemsetAsync(ws + ZERO0, 0, ZEROB, stream);

  k_w2t<<<(896 * 96 + 255) / 256, 256, 0, stream>>>(W2, w2t);
  k_w1t<<<(96 * 96 + 255) / 256, 256, 0, stream>>>(W1, w1h, w1l);
  k_wsplit<2 * DHID, KP1, DF1><<<(KP1 / 32) * (DF1 / 32), 256, 0, stream>>>(Wg1, g1h, g1l);
  k_wsplit<DF1, DF1, DOUTC><<<(DF1 / 32) * (DOUTC / 32), 256, 0, stream>>>(Wg2, g2h, g2l);
  k_xbf<<<(N_NODES * 24 + 255) / 256, 256, 0, stream>>>(x, xb);

  int nbb = (N_EDGESC + EPB - 1) / EPB;   // 98
  k_bhist<<<nbb, 256, 0, stream>>>(dst, bcnt);
  k_bscan<<<1, 512, 0, stream>>>(bcnt, boff, bcur);
  k_bfill<<<nbb, 256, 0, stream>>>(src, dst, bcur, rec);
  k_bsort<<<NBUCK, 256, 0, stream>>>(rec, boff, rowptr, csr);
  k_counts<<<(N_NODES + 2047) / 2048, 256, 0, stream>>>(batch, cnt);

  k_agg1b<<<(N_NODES + 7) / 8, 256, 0, stream>>>(xb, rowptr, csr, agg);
  k_conv1m<<<(N_NODES + 63) / 64, 256, 0, stream>>>(agg, w1h, w1l, b1, h1b);
  k_agg2<<<(N_NODES + 7) / 8, 256, 0, stream>>>(h1b, rowptr, csr, aggb);
  k_conv2pool3<<<PBLK2, 256, 0, stream>>>(aggb, w2t, b2, batch, pm0, ps0, pm1, ps1, blkg, maxb, sump);
  k_pool2<<<NGRAPH, 256, 0, stream>>>(pm0, ps0, pm1, ps1, blkg, cnt, maxb, sump, zh, zl);

  k_mlp1m<<<(DF1 / 16) * 2, 256, 0, stream>>>(zh, zl, g1h, g1l, bg1, z1h, z1l);
  k_mlp2m<<<(DOUTC / 16) * 2, 256, 0, stream>>>(z1h, z1l, g2h, g2l, bg2, out);
}